// Round 1
// baseline (21561.897 us; speedup 1.0000x reference)
//
#include <hip/hip_runtime.h>

#define NN 100000
#define NE 1600000
#define C 64
#define CIN 66   // C + 2
#define NCLS 101
#define EPS_BN 1e-5f

// ---------------------------------------------------------------------------
// Per-edge feature load: feat[0..63] = x[src], feat[64..65] = pos2[src]-pos2[dst]
// ---------------------------------------------------------------------------
__device__ __forceinline__ void load_feat(const float* __restrict__ x,
                                          const float* __restrict__ pos,
                                          int s, int d, float feat[CIN]) {
    const float4* xr = (const float4*)(x + (size_t)s * C);
#pragma unroll
    for (int j = 0; j < C / 4; ++j) {
        float4 v = xr[j];
        feat[4 * j + 0] = v.x;
        feat[4 * j + 1] = v.y;
        feat[4 * j + 2] = v.z;
        feat[4 * j + 3] = v.w;
    }
    feat[64] = pos[s * 3 + 0] - pos[d * 3 + 0];
    feat[65] = pos[s * 3 + 1] - pos[d * 3 + 1];
}

// ---------------------------------------------------------------------------
// m = relu(wl @ feat + bl); atomic segment-max into agg[d]. relu output >= 0,
// so int-compare atomicMax on the float bit pattern is order-correct, and
// 0-initialized agg reproduces the where(isfinite, ., 0) empty-node semantics.
// ---------------------------------------------------------------------------
template <int COUT>
__device__ __forceinline__ void conv_scatter(const float* __restrict__ wl,
                                             const float* __restrict__ bl,
                                             const float feat[CIN], int d,
                                             float* __restrict__ agg) {
    int* ai = (int*)(agg + (size_t)d * COUT);
    int c = 0;
    for (; c + 4 <= COUT; c += 4) {
        float a0 = bl[c + 0], a1 = bl[c + 1], a2 = bl[c + 2], a3 = bl[c + 3];
        const float* w0 = wl + (size_t)c * CIN;
        const float* w1 = w0 + CIN;
        const float* w2 = w1 + CIN;
        const float* w3 = w2 + CIN;
#pragma unroll
        for (int j = 0; j < CIN; ++j) {
            float f = feat[j];
            a0 = fmaf(f, w0[j], a0);
            a1 = fmaf(f, w1[j], a1);
            a2 = fmaf(f, w2[j], a2);
            a3 = fmaf(f, w3[j], a3);
        }
        atomicMax(ai + c + 0, __float_as_int(fmaxf(a0, 0.0f)));
        atomicMax(ai + c + 1, __float_as_int(fmaxf(a1, 0.0f)));
        atomicMax(ai + c + 2, __float_as_int(fmaxf(a2, 0.0f)));
        atomicMax(ai + c + 3, __float_as_int(fmaxf(a3, 0.0f)));
    }
    for (; c < COUT; ++c) {
        float a0 = bl[c];
        const float* w0 = wl + (size_t)c * CIN;
#pragma unroll
        for (int j = 0; j < CIN; ++j) a0 = fmaf(feat[j], w0[j], a0);
        atomicMax(ai + c, __float_as_int(fmaxf(a0, 0.0f)));
    }
}

template <int COUT>
__global__ __launch_bounds__(256) void edge_conv_k(
    const float* __restrict__ x, const float* __restrict__ pos,
    const int* __restrict__ src, const int* __restrict__ dst,
    const float* __restrict__ wl, const float* __restrict__ bl,
    float* __restrict__ agg) {
    int e = blockIdx.x * 256 + threadIdx.x;
    if (e >= NE) return;
    int s = src[e], d = dst[e];
    float feat[CIN];
    load_feat(x, pos, s, d, feat);
    conv_scatter<COUT>(wl, bl, feat, d, agg);
}

__global__ __launch_bounds__(256) void edge_conv_c1c2_k(
    const float* __restrict__ h, const float* __restrict__ pos,
    const int* __restrict__ src, const int* __restrict__ dst,
    const float* __restrict__ wl1, const float* __restrict__ bl1,
    const float* __restrict__ wl2, const float* __restrict__ bl2,
    float* __restrict__ a1, float* __restrict__ a2) {
    int e = blockIdx.x * 256 + threadIdx.x;
    if (e >= NE) return;
    int s = src[e], d = dst[e];
    float feat[CIN];
    load_feat(h, pos, s, d, feat);
    conv_scatter<C>(wl1, bl1, feat, d, a1);
    conv_scatter<C>(wl2, bl2, feat, d, a2);
}

__global__ __launch_bounds__(256) void edge_conv_regobj_k(
    const float* __restrict__ x1, const float* __restrict__ pos,
    const int* __restrict__ src, const int* __restrict__ dst,
    const float* __restrict__ wlr, const float* __restrict__ blr,
    const float* __restrict__ wlo, const float* __restrict__ blo,
    float* __restrict__ aggr, float* __restrict__ aggo) {
    int e = blockIdx.x * 256 + threadIdx.x;
    if (e >= NE) return;
    int s = src[e], d = dst[e];
    float feat[CIN];
    load_feat(x1, pos, s, d, feat);
    conv_scatter<4>(wlr, blr, feat, d, aggr);
    conv_scatter<1>(wlo, blo, feat, d, aggo);
}

// ---------------------------------------------------------------------------
// out[n] = agg[n] @ wg.T + bg, written in place; accumulate per-channel
// sum / sumsq into stats[0..C) / stats[C..2C) via wave reduce + atomicAdd.
// ---------------------------------------------------------------------------
__global__ __launch_bounds__(256) void node_linear_stats_k(
    float* __restrict__ agg, const float* __restrict__ wg,
    const float* __restrict__ bg, float* __restrict__ stats) {
    int n = blockIdx.x * 256 + threadIdx.x;
    bool active = n < NN;
    float a[C];
    if (active) {
        const float4* r = (const float4*)(agg + (size_t)n * C);
#pragma unroll
        for (int j = 0; j < C / 4; ++j) {
            float4 v = r[j];
            a[4 * j + 0] = v.x;
            a[4 * j + 1] = v.y;
            a[4 * j + 2] = v.z;
            a[4 * j + 3] = v.w;
        }
    } else {
#pragma unroll
        for (int j = 0; j < C; ++j) a[j] = 0.0f;
    }
    int lane = threadIdx.x & 63;
    for (int c = 0; c < C; c += 4) {
        float o[4];
#pragma unroll
        for (int k = 0; k < 4; ++k) {
            float acc = active ? bg[c + k] : 0.0f;
            const float* w = wg + (size_t)(c + k) * C;
#pragma unroll
            for (int j = 0; j < C; ++j) acc = fmaf(a[j], w[j], acc);
            o[k] = active ? acc : 0.0f;
        }
        if (active) {
#pragma unroll
            for (int k = 0; k < 4; ++k) agg[(size_t)n * C + c + k] = o[k];
        }
#pragma unroll
        for (int k = 0; k < 4; ++k) {
            float sv = o[k];
            float qv = o[k] * o[k];
            for (int off = 32; off > 0; off >>= 1) {
                sv += __shfl_down(sv, off, 64);
                qv += __shfl_down(qv, off, 64);
            }
            if (lane == 0) {
                atomicAdd(&stats[c + k], sv);
                atomicAdd(&stats[C + c + k], qv);
            }
        }
    }
}

__global__ __launch_bounds__(256) void bn_relu_k(
    float* __restrict__ x, const float* __restrict__ stats,
    const float* __restrict__ g, const float* __restrict__ b) {
    int i = blockIdx.x * 256 + threadIdx.x;
    if (i >= NN * C) return;
    int c = i & (C - 1);
    float mu = stats[c] * (1.0f / NN);
    float var = stats[C + c] * (1.0f / NN) - mu * mu;
    float rs = rsqrtf(var + EPS_BN);
    float v = (x[i] - mu) * rs * g[c] + b[c];
    x[i] = fmaxf(v, 0.0f);
}

// ---------------------------------------------------------------------------
// Final heads: cls = aggc @ wgc.T + bgc (101x101), reg 4x4, obj 1x1.
// d_out layout: [cls (N*101) | reg (N*4) | obj (N*1)]
// ---------------------------------------------------------------------------
__global__ __launch_bounds__(256) void final_k(
    const float* __restrict__ aggc, const float* __restrict__ aggr,
    const float* __restrict__ aggo, const float* __restrict__ wgc,
    const float* __restrict__ bgc, const float* __restrict__ wgr,
    const float* __restrict__ bgr, const float* __restrict__ wgo,
    const float* __restrict__ bgo, float* __restrict__ out) {
    int n = blockIdx.x * 256 + threadIdx.x;
    if (n >= NN) return;
    float ac[NCLS];
#pragma unroll 4
    for (int j = 0; j < NCLS; ++j) ac[j] = aggc[(size_t)n * NCLS + j];
    float* cls = out;
    float* reg = out + (size_t)NN * NCLS;
    float* obj = out + (size_t)NN * (NCLS + 4);
    int k = 0;
    for (; k + 4 <= NCLS; k += 4) {
        float a0 = bgc[k + 0], a1 = bgc[k + 1], a2 = bgc[k + 2], a3 = bgc[k + 3];
        const float* w0 = wgc + (size_t)k * NCLS;
        const float* w1 = w0 + NCLS;
        const float* w2 = w1 + NCLS;
        const float* w3 = w2 + NCLS;
        for (int j = 0; j < NCLS; ++j) {
            float f = ac[j];
            a0 = fmaf(f, w0[j], a0);
            a1 = fmaf(f, w1[j], a1);
            a2 = fmaf(f, w2[j], a2);
            a3 = fmaf(f, w3[j], a3);
        }
        cls[(size_t)n * NCLS + k + 0] = a0;
        cls[(size_t)n * NCLS + k + 1] = a1;
        cls[(size_t)n * NCLS + k + 2] = a2;
        cls[(size_t)n * NCLS + k + 3] = a3;
    }
    for (; k < NCLS; ++k) {
        float a0 = bgc[k];
        const float* w0 = wgc + (size_t)k * NCLS;
        for (int j = 0; j < NCLS; ++j) a0 = fmaf(ac[j], w0[j], a0);
        cls[(size_t)n * NCLS + k] = a0;
    }
    float ar[4];
#pragma unroll
    for (int j = 0; j < 4; ++j) ar[j] = aggr[(size_t)n * 4 + j];
#pragma unroll
    for (int kk = 0; kk < 4; ++kk) {
        float acc = bgr[kk];
#pragma unroll
        for (int j = 0; j < 4; ++j) acc = fmaf(ar[j], wgr[kk * 4 + j], acc);
        reg[(size_t)n * 4 + kk] = acc;
    }
    obj[n] = fmaf(aggo[n], wgo[0], bgo[0]);
}

// ---------------------------------------------------------------------------
extern "C" void kernel_launch(void* const* d_in, const int* in_sizes, int n_in,
                              void* d_out, int out_size, void* d_ws, size_t ws_size,
                              hipStream_t stream) {
    const float* x   = (const float*)d_in[0];
    const float* pos = (const float*)d_in[1];
    const int* ei    = (const int*)d_in[2];
    const int* src = ei;
    const int* dst = ei + NE;
    const float* wl_stem = (const float*)d_in[3];
    const float* bl_stem = (const float*)d_in[4];
    const float* wg_stem = (const float*)d_in[5];
    const float* bg_stem = (const float*)d_in[6];
    const float* g_stem  = (const float*)d_in[7];
    const float* b_stem  = (const float*)d_in[8];
    const float* wl_c1 = (const float*)d_in[9];
    const float* bl_c1 = (const float*)d_in[10];
    const float* wg_c1 = (const float*)d_in[11];
    const float* bg_c1 = (const float*)d_in[12];
    const float* g_c1  = (const float*)d_in[13];
    const float* b_c1  = (const float*)d_in[14];
    const float* wl_c2 = (const float*)d_in[15];
    const float* bl_c2 = (const float*)d_in[16];
    const float* wg_c2 = (const float*)d_in[17];
    const float* bg_c2 = (const float*)d_in[18];
    const float* g_c2  = (const float*)d_in[19];
    const float* b_c2  = (const float*)d_in[20];
    const float* wl_reg = (const float*)d_in[21];
    const float* bl_reg = (const float*)d_in[22];
    const float* wg_reg = (const float*)d_in[23];
    const float* bg_reg = (const float*)d_in[24];
    const float* wl_cls = (const float*)d_in[25];
    const float* bl_cls = (const float*)d_in[26];
    const float* wg_cls = (const float*)d_in[27];
    const float* bg_cls = (const float*)d_in[28];
    const float* wl_obj = (const float*)d_in[29];
    const float* bl_obj = (const float*)d_in[30];
    const float* wg_obj = (const float*)d_in[31];
    const float* bg_obj = (const float*)d_in[32];

    float* ws = (float*)d_ws;
    float* h    = ws;                          // N*C   (aggS -> h_pre -> h, in place)
    float* a1   = h + (size_t)NN * C;          // N*C   (agg1 -> x1)
    float* a2   = a1 + (size_t)NN * C;         // N*C   (agg2 -> x2)
    float* aggc = a2 + (size_t)NN * C;         // N*101
    float* aggr = aggc + (size_t)NN * NCLS;    // N*4
    float* aggo = aggr + (size_t)NN * 4;       // N
    float* stats = aggo + NN;                  // 6*C  (sum/sumsq for stem, c1, c2)
    size_t total_bytes = (size_t)((stats + 6 * C) - ws) * sizeof(float);  // ~119.2 MB

    hipMemsetAsync(d_ws, 0, total_bytes, stream);

    const int EB = (NE + 255) / 256;    // 6250
    const int NB = (NN + 255) / 256;    // 391
    const int XB = (NN * C + 255) / 256;

    edge_conv_k<C><<<EB, 256, 0, stream>>>(x, pos, src, dst, wl_stem, bl_stem, h);
    node_linear_stats_k<<<NB, 256, 0, stream>>>(h, wg_stem, bg_stem, stats);
    bn_relu_k<<<XB, 256, 0, stream>>>(h, stats, g_stem, b_stem);

    edge_conv_c1c2_k<<<EB, 256, 0, stream>>>(h, pos, src, dst, wl_c1, bl_c1,
                                             wl_c2, bl_c2, a1, a2);
    node_linear_stats_k<<<NB, 256, 0, stream>>>(a1, wg_c1, bg_c1, stats + 2 * C);
    node_linear_stats_k<<<NB, 256, 0, stream>>>(a2, wg_c2, bg_c2, stats + 4 * C);
    bn_relu_k<<<XB, 256, 0, stream>>>(a1, stats + 2 * C, g_c1, b_c1);
    bn_relu_k<<<XB, 256, 0, stream>>>(a2, stats + 4 * C, g_c2, b_c2);

    edge_conv_regobj_k<<<EB, 256, 0, stream>>>(a1, pos, src, dst, wl_reg, bl_reg,
                                               wl_obj, bl_obj, aggr, aggo);
    edge_conv_k<NCLS><<<EB, 256, 0, stream>>>(a2, pos, src, dst, wl_cls, bl_cls, aggc);

    final_k<<<NB, 256, 0, stream>>>(aggc, aggr, aggo, wg_cls, bg_cls,
                                    wg_reg, bg_reg, wg_obj, bg_obj, (float*)d_out);
}

// Round 2
// 2052.174 us; speedup vs baseline: 10.5069x; 10.5069x over previous
//
#include <hip/hip_runtime.h>

#define NN 100000
#define NE 1600000
#define C 64
#define NCLS 101
#define EPS_BN 1e-5f
#define NB_SCAN 391   // ceil(NN/256)

// ============================================================================
// CSR build: histogram -> block scan -> global scan -> scatter
// ============================================================================
__global__ __launch_bounds__(256) void hist_k(const int* __restrict__ dst,
                                              int* __restrict__ cnt) {
    int e = blockIdx.x * 256 + threadIdx.x;
    if (e < NE) atomicAdd(&cnt[dst[e]], 1);
}

__global__ __launch_bounds__(256) void scan1_k(const int* __restrict__ cnt,
                                               int* __restrict__ rs,
                                               int* __restrict__ blk) {
    __shared__ int sh[256];
    int t = threadIdx.x;
    int i = blockIdx.x * 256 + t;
    int v = (i < NN) ? cnt[i] : 0;
    sh[t] = v;
    __syncthreads();
    for (int off = 1; off < 256; off <<= 1) {
        int u = (t >= off) ? sh[t - off] : 0;
        __syncthreads();
        sh[t] += u;
        __syncthreads();
    }
    if (i < NN) rs[i] = sh[t] - v;   // exclusive within block
    if (t == 255) blk[blockIdx.x] = sh[255];
}

__global__ __launch_bounds__(512) void scan2_k(int* __restrict__ blk) {
    __shared__ int sh[512];
    int t = threadIdx.x;
    int v = (t < NB_SCAN) ? blk[t] : 0;
    sh[t] = v;
    __syncthreads();
    for (int off = 1; off < 512; off <<= 1) {
        int u = (t >= off) ? sh[t - off] : 0;
        __syncthreads();
        sh[t] += u;
        __syncthreads();
    }
    if (t < NB_SCAN) blk[t] = sh[t] - v;  // exclusive block offsets
}

__global__ __launch_bounds__(256) void scan3_k(int* __restrict__ rs,
                                               const int* __restrict__ blk,
                                               int* __restrict__ cur) {
    int i = blockIdx.x * 256 + threadIdx.x;
    if (i < NN) {
        int v = rs[i] + blk[i >> 8];
        rs[i] = v;
        cur[i] = v;                  // cursor copy for scatter
    } else if (i == NN) {
        rs[NN] = NE;
    }
}

__global__ __launch_bounds__(256) void scatter_k(const int* __restrict__ src,
                                                 const int* __restrict__ dst,
                                                 int* __restrict__ cur,
                                                 int* __restrict__ csrc) {
    int e = blockIdx.x * 256 + threadIdx.x;
    if (e >= NE) return;
    int d = dst[e];
    int p = atomicAdd(&cur[d], 1);
    csrc[p] = src[e];
}

// ============================================================================
// Node-side GEMM: out[n][c] = sum_j in[n][j]*w[c][j] + b[c]
// Tile of 64 nodes in LDS ([j][n], pad 65 -> conflict-free); weights are
// wave-uniform -> scalar loads. wave = 16..26 output channels, lane = node.
// In-place safe (each block touches only its own 64 rows, after barrier).
// ============================================================================
template <int COUT, int CPW, int K, int IS, int WS, int OS>
__global__ __launch_bounds__(256) void lin_k(const float* __restrict__ in,
                                             const float* __restrict__ w,
                                             const float* __restrict__ b,
                                             float* __restrict__ out) {
    __shared__ float xs[K * 65];
    int base = blockIdx.x * 64;
    for (int p = threadIdx.x; p < 64 * K; p += 256) {
        int n = p / K, j = p - n * K;
        xs[j * 65 + n] = (base + n < NN) ? in[(size_t)(base + n) * IS + j] : 0.f;
    }
    __syncthreads();
    int wid = threadIdx.x >> 6, lane = threadIdx.x & 63;
    int node = base + lane;
    int c0 = wid * CPW;
    float acc[CPW];
#pragma unroll
    for (int k = 0; k < CPW; ++k) acc[k] = (c0 + k < COUT) ? b[c0 + k] : 0.f;
    for (int j = 0; j < K; ++j) {
        float xv = xs[j * 65 + lane];
#pragma unroll
        for (int k = 0; k < CPW; ++k)
            acc[k] = fmaf(xv, (c0 + k < COUT) ? w[(size_t)(c0 + k) * WS + j] : 0.f,
                          acc[k]);
    }
    if (node < NN) {
#pragma unroll
        for (int k = 0; k < CPW; ++k)
            if (c0 + k < COUT) out[(size_t)node * OS + c0 + k] = acc[k];
    }
}

// ============================================================================
// Edge segment-max passes over CSR. wave per node, lane = channel.
// m = y[src][c] + dpx*wp0[c] + dpy*wp1[c]; agg = relu(max(m)) (empty -> 0).
// ============================================================================
__global__ __launch_bounds__(256) void edge1_k(const float* __restrict__ y,
                                               const float* __restrict__ pos,
                                               const int* __restrict__ rs,
                                               const int* __restrict__ csrc,
                                               const float* __restrict__ wl,  // (64,66)
                                               float* __restrict__ agg) {
    int wid = threadIdx.x >> 6, lane = threadIdx.x & 63;
    int node = blockIdx.x * 4 + wid;
    if (node >= NN) return;
    float wp0 = wl[lane * 66 + 64];
    float wp1 = wl[lane * 66 + 65];
    float pdx = pos[node * 3 + 0];
    float pdy = pos[node * 3 + 1];
    int i0 = rs[node], i1 = rs[node + 1];
    float acc = -__builtin_inff();
    int i = i0;
    for (; i + 2 <= i1; i += 2) {
        int s0 = csrc[i], s1 = csrc[i + 1];
        float dx0 = pos[s0 * 3] - pdx, dy0 = pos[s0 * 3 + 1] - pdy;
        float dx1 = pos[s1 * 3] - pdx, dy1 = pos[s1 * 3 + 1] - pdy;
        float v0 = y[(size_t)s0 * 64 + lane];
        float v1 = y[(size_t)s1 * 64 + lane];
        v0 = fmaf(dy0, wp1, fmaf(dx0, wp0, v0));
        v1 = fmaf(dy1, wp1, fmaf(dx1, wp0, v1));
        acc = fmaxf(acc, fmaxf(v0, v1));
    }
    if (i < i1) {
        int s0 = csrc[i];
        float dx0 = pos[s0 * 3] - pdx, dy0 = pos[s0 * 3 + 1] - pdy;
        float v0 = fmaf(dy0, wp1, fmaf(dx0, wp0, y[(size_t)s0 * 64 + lane]));
        acc = fmaxf(acc, v0);
    }
    agg[(size_t)node * 64 + lane] = fmaxf(acc, 0.0f);
}

__global__ __launch_bounds__(256) void edge2_k(const float* __restrict__ y1,
                                               const float* __restrict__ y2,
                                               const float* __restrict__ pos,
                                               const int* __restrict__ rs,
                                               const int* __restrict__ csrc,
                                               const float* __restrict__ wlA,
                                               const float* __restrict__ wlB,
                                               float* __restrict__ a1,
                                               float* __restrict__ a2) {
    int wid = threadIdx.x >> 6, lane = threadIdx.x & 63;
    int node = blockIdx.x * 4 + wid;
    if (node >= NN) return;
    float wa0 = wlA[lane * 66 + 64], wa1 = wlA[lane * 66 + 65];
    float wb0 = wlB[lane * 66 + 64], wb1 = wlB[lane * 66 + 65];
    float pdx = pos[node * 3 + 0], pdy = pos[node * 3 + 1];
    int i0 = rs[node], i1 = rs[node + 1];
    float accA = -__builtin_inff(), accB = -__builtin_inff();
    for (int i = i0; i < i1; ++i) {
        int s = csrc[i];
        float dx = pos[s * 3] - pdx, dy = pos[s * 3 + 1] - pdy;
        float u = y1[(size_t)s * 64 + lane];
        float v = y2[(size_t)s * 64 + lane];
        accA = fmaxf(accA, fmaf(dy, wa1, fmaf(dx, wa0, u)));
        accB = fmaxf(accB, fmaf(dy, wb1, fmaf(dx, wb0, v)));
    }
    a1[(size_t)node * 64 + lane] = fmaxf(accA, 0.0f);
    a2[(size_t)node * 64 + lane] = fmaxf(accB, 0.0f);
}

__global__ __launch_bounds__(256) void edge_cls_k(const float* __restrict__ y,  // stride 104
                                                  const float* __restrict__ pos,
                                                  const int* __restrict__ rs,
                                                  const int* __restrict__ csrc,
                                                  const float* __restrict__ wl,  // (101,66)
                                                  float* __restrict__ agg) {     // stride 104
    int half = threadIdx.x >> 7;       // 2 nodes / block
    int t = threadIdx.x & 127;
    int node = blockIdx.x * 2 + half;
    if (node >= NN) return;
    bool act = t < NCLS;
    float wp0 = act ? wl[t * 66 + 64] : 0.f;
    float wp1 = act ? wl[t * 66 + 65] : 0.f;
    float pdx = pos[node * 3 + 0], pdy = pos[node * 3 + 1];
    int i0 = rs[node], i1 = rs[node + 1];
    float acc = -__builtin_inff();
    for (int i = i0; i < i1; ++i) {
        int s = csrc[i];
        float dx = pos[s * 3] - pdx, dy = pos[s * 3 + 1] - pdy;
        float v = act ? y[(size_t)s * 104 + t] : 0.f;
        acc = fmaxf(acc, fmaf(dy, wp1, fmaf(dx, wp0, v)));
    }
    if (act) agg[(size_t)node * 104 + t] = fmaxf(acc, 0.0f);
}

// reg+obj: 5 channels packed stride 8; wave = 8 edge-slots x 8 channel-slots
__global__ __launch_bounds__(256) void edge_ro_k(const float* __restrict__ y,  // stride 8
                                                 const float* __restrict__ pos,
                                                 const int* __restrict__ rs,
                                                 const int* __restrict__ csrc,
                                                 const float* __restrict__ wro,  // (5,66)
                                                 float* __restrict__ aggr,
                                                 float* __restrict__ aggo) {
    int wid = threadIdx.x >> 6, lane = threadIdx.x & 63;
    int node = blockIdx.x * 4 + wid;
    if (node >= NN) return;
    int k = lane >> 3, c = lane & 7;
    float wp0 = (c < 5) ? wro[c * 66 + 64] : 0.f;
    float wp1 = (c < 5) ? wro[c * 66 + 65] : 0.f;
    float pdx = pos[node * 3 + 0], pdy = pos[node * 3 + 1];
    int i0 = rs[node], i1 = rs[node + 1];
    float acc = -__builtin_inff();
    for (int i = i0 + k; i < i1; i += 8) {
        int s = csrc[i];
        float dx = pos[s * 3] - pdx, dy = pos[s * 3 + 1] - pdy;
        float v = (c < 5) ? y[(size_t)s * 8 + c] : 0.f;
        acc = fmaxf(acc, fmaf(dy, wp1, fmaf(dx, wp0, v)));
    }
    acc = fmaxf(acc, __shfl_xor(acc, 8, 64));
    acc = fmaxf(acc, __shfl_xor(acc, 16, 64));
    acc = fmaxf(acc, __shfl_xor(acc, 32, 64));
    acc = fmaxf(acc, 0.0f);
    if (lane < 5) {
        if (lane < 4) aggr[(size_t)node * 4 + lane] = acc;
        else          aggo[node] = acc;
    }
}

// ============================================================================
// BN: column sums -> params -> apply
// ============================================================================
__global__ __launch_bounds__(256) void stats_k(const float* __restrict__ x,
                                               float* __restrict__ st) {
    __shared__ float sS[4][64], sQ[4][64];
    int wid = threadIdx.x >> 6, lane = threadIdx.x & 63;
    float s = 0.f, q = 0.f;
    for (int n = blockIdx.x * 4 + wid; n < NN; n += 512) {
        float v = x[(size_t)n * 64 + lane];
        s += v;
        q = fmaf(v, v, q);
    }
    sS[wid][lane] = s;
    sQ[wid][lane] = q;
    __syncthreads();
    if (wid == 0) {
        float ts = sS[0][lane] + sS[1][lane] + sS[2][lane] + sS[3][lane];
        float tq = sQ[0][lane] + sQ[1][lane] + sQ[2][lane] + sQ[3][lane];
        atomicAdd(&st[lane], ts);
        atomicAdd(&st[64 + lane], tq);
    }
}

__global__ void bnpar_k(float* __restrict__ st, const float* __restrict__ g,
                        const float* __restrict__ b) {
    int c = threadIdx.x;
    if (c >= 64) return;
    float mu = st[c] * (1.0f / NN);
    float var = st[64 + c] * (1.0f / NN) - mu * mu;
    float sc = g[c] * rsqrtf(var + EPS_BN);
    st[128 + c] = sc;
    st[192 + c] = b[c] - mu * sc;
}

__global__ __launch_bounds__(256) void bnrelu_k(float* __restrict__ x,
                                                const float* __restrict__ st) {
    int i = blockIdx.x * 256 + threadIdx.x;   // over NN*16 float4s
    if (i >= NN * 16) return;
    float4 v = ((float4*)x)[i];
    int c0 = (i * 4) & 63;
    v.x = fmaxf(fmaf(v.x, st[128 + c0 + 0], st[192 + c0 + 0]), 0.f);
    v.y = fmaxf(fmaf(v.y, st[128 + c0 + 1], st[192 + c0 + 1]), 0.f);
    v.z = fmaxf(fmaf(v.z, st[128 + c0 + 2], st[192 + c0 + 2]), 0.f);
    v.w = fmaxf(fmaf(v.w, st[128 + c0 + 3], st[192 + c0 + 3]), 0.f);
    ((float4*)x)[i] = v;
}

// pack reg(4)+obj(1) weights into one (5,66) matrix + (5,) bias
__global__ void pack_ro_k(const float* __restrict__ wlr, const float* __restrict__ blr,
                          const float* __restrict__ wlo, const float* __restrict__ blo,
                          float* __restrict__ wro, float* __restrict__ bro) {
    int t = threadIdx.x;
    if (t < 5 * 66) {
        int cc = t / 66, j = t - cc * 66;
        wro[t] = (cc < 4) ? wlr[t] : wlo[j];
    }
    if (t < 5) bro[t] = (t < 4) ? blr[t] : blo[0];
}

// reg/obj heads: tiny per-node matvec
__global__ __launch_bounds__(256) void final_ro_k(const float* __restrict__ aggr,
                                                  const float* __restrict__ aggo,
                                                  const float* __restrict__ wgr,
                                                  const float* __restrict__ bgr,
                                                  const float* __restrict__ wgo,
                                                  const float* __restrict__ bgo,
                                                  float* __restrict__ out) {
    int n = blockIdx.x * 256 + threadIdx.x;
    if (n >= NN) return;
    float a0 = aggr[(size_t)n * 4 + 0], a1 = aggr[(size_t)n * 4 + 1];
    float a2 = aggr[(size_t)n * 4 + 2], a3 = aggr[(size_t)n * 4 + 3];
    float* reg = out + (size_t)NN * NCLS;
    float* obj = reg + (size_t)NN * 4;
#pragma unroll
    for (int k = 0; k < 4; ++k) {
        float acc = bgr[k];
        acc = fmaf(a0, wgr[k * 4 + 0], acc);
        acc = fmaf(a1, wgr[k * 4 + 1], acc);
        acc = fmaf(a2, wgr[k * 4 + 2], acc);
        acc = fmaf(a3, wgr[k * 4 + 3], acc);
        reg[(size_t)n * 4 + k] = acc;
    }
    obj[n] = fmaf(aggo[n], wgo[0], bgo[0]);
}

// ============================================================================
extern "C" void kernel_launch(void* const* d_in, const int* in_sizes, int n_in,
                              void* d_out, int out_size, void* d_ws, size_t ws_size,
                              hipStream_t stream) {
    const float* x   = (const float*)d_in[0];
    const float* pos = (const float*)d_in[1];
    const int* ei    = (const int*)d_in[2];
    const int* src = ei;
    const int* dst = ei + NE;
    const float* wl_stem = (const float*)d_in[3];
    const float* bl_stem = (const float*)d_in[4];
    const float* wg_stem = (const float*)d_in[5];
    const float* bg_stem = (const float*)d_in[6];
    const float* g_stem  = (const float*)d_in[7];
    const float* b_stem  = (const float*)d_in[8];
    const float* wl_c1 = (const float*)d_in[9];
    const float* bl_c1 = (const float*)d_in[10];
    const float* wg_c1 = (const float*)d_in[11];
    const float* bg_c1 = (const float*)d_in[12];
    const float* g_c1  = (const float*)d_in[13];
    const float* b_c1  = (const float*)d_in[14];
    const float* wl_c2 = (const float*)d_in[15];
    const float* bl_c2 = (const float*)d_in[16];
    const float* wg_c2 = (const float*)d_in[17];
    const float* bg_c2 = (const float*)d_in[18];
    const float* g_c2  = (const float*)d_in[19];
    const float* b_c2  = (const float*)d_in[20];
    const float* wl_reg = (const float*)d_in[21];
    const float* bl_reg = (const float*)d_in[22];
    const float* wg_reg = (const float*)d_in[23];
    const float* bg_reg = (const float*)d_in[24];
    const float* wl_cls = (const float*)d_in[25];
    const float* bl_cls = (const float*)d_in[26];
    const float* wg_cls = (const float*)d_in[27];
    const float* bg_cls = (const float*)d_in[28];
    const float* wl_obj = (const float*)d_in[29];
    const float* bl_obj = (const float*)d_in[30];
    const float* wg_obj = (const float*)d_in[31];
    const float* bg_obj = (const float*)d_in[32];

    float* ws = (float*)d_ws;
    // Big slots (N*64 each). y_cls spans B3+B4 (N*104 <= 2*N*64); aggc spans B1+B2.
    float* B1 = ws;
    float* B2 = B1 + (size_t)NN * 64;
    float* B3 = B2 + (size_t)NN * 64;
    float* B4 = B3 + (size_t)NN * 64;
    float* y_cls = B3;
    float* aggc  = B1;
    int*   rs   = (int*)(B4 + (size_t)NN * 64);   // NN+1 (padded to 100016)
    int*   cnt  = rs + 100016;                    // NN (histogram, then cursor)
    int*   csrc = cnt + 100016;                   // NE
    float* y_ro = (float*)(csrc + NE);            // NN*8
    float* aggr = y_ro + (size_t)NN * 8;          // NN*4
    float* aggo = aggr + (size_t)NN * 4;          // NN
    float* st   = aggo + NN;                      // 3 * 256
    float* st0 = st, *st1 = st + 256, *st2 = st + 512;
    float* wro = st + 768;                        // 5*66
    float* bro = wro + 330;                       // 5
    int*   blk = (int*)(bro + 16);                // 512 scan block sums

    hipMemsetAsync(cnt, 0, 100016 * sizeof(int), stream);
    hipMemsetAsync(st, 0, 768 * sizeof(float), stream);

    const int EB = (NE + 255) / 256;      // 6250
    const int NB = (NN + 255) / 256;      // 391
    const int N4 = (NN + 3) / 4;          // 25000
    const int N2 = (NN + 1) / 2;          // 50000
    const int NT = (NN + 63) / 64;        // 1563 tiles
    const int XB = NN * 16 / 256;         // 6250 (float4 elementwise)

    // ---- CSR build ----
    hist_k<<<EB, 256, 0, stream>>>(dst, cnt);
    scan1_k<<<NB_SCAN, 256, 0, stream>>>(cnt, rs, blk);
    scan2_k<<<1, 512, 0, stream>>>(blk);
    scan3_k<<<NB + 1, 256, 0, stream>>>(rs, blk, cnt);
    scatter_k<<<EB, 256, 0, stream>>>(src, dst, cnt, csrc);

    // ---- stem ----
    lin_k<64, 16, 64, 64, 66, 64><<<NT, 256, 0, stream>>>(x, wl_stem, bl_stem, B1);
    edge1_k<<<N4, 256, 0, stream>>>(B1, pos, rs, csrc, wl_stem, B2);
    lin_k<64, 16, 64, 64, 64, 64><<<NT, 256, 0, stream>>>(B2, wg_stem, bg_stem, B2);
    stats_k<<<128, 256, 0, stream>>>(B2, st0);
    bnpar_k<<<1, 64, 0, stream>>>(st0, g_stem, b_stem);
    bnrelu_k<<<XB, 256, 0, stream>>>(B2, st0);

    // ---- c1 + c2 (shared edge pass) ----
    lin_k<64, 16, 64, 64, 66, 64><<<NT, 256, 0, stream>>>(B2, wl_c1, bl_c1, B3);
    lin_k<64, 16, 64, 64, 66, 64><<<NT, 256, 0, stream>>>(B2, wl_c2, bl_c2, B4);
    edge2_k<<<N4, 256, 0, stream>>>(B3, B4, pos, rs, csrc, wl_c1, wl_c2, B1, B2);
    lin_k<64, 16, 64, 64, 64, 64><<<NT, 256, 0, stream>>>(B1, wg_c1, bg_c1, B1);
    stats_k<<<128, 256, 0, stream>>>(B1, st1);
    bnpar_k<<<1, 64, 0, stream>>>(st1, g_c1, b_c1);
    bnrelu_k<<<XB, 256, 0, stream>>>(B1, st1);
    lin_k<64, 16, 64, 64, 64, 64><<<NT, 256, 0, stream>>>(B2, wg_c2, bg_c2, B2);
    stats_k<<<128, 256, 0, stream>>>(B2, st2);
    bnpar_k<<<1, 64, 0, stream>>>(st2, g_c2, b_c2);
    bnrelu_k<<<XB, 256, 0, stream>>>(B2, st2);

    // ---- reg + obj heads (input x1 = B1) ----
    pack_ro_k<<<1, 512, 0, stream>>>(wl_reg, bl_reg, wl_obj, bl_obj, wro, bro);
    lin_k<5, 2, 64, 64, 66, 8><<<NT, 256, 0, stream>>>(B1, wro, bro, y_ro);
    edge_ro_k<<<N4, 256, 0, stream>>>(y_ro, pos, rs, csrc, wro, aggr, aggo);

    // ---- cls head (input x2 = B2) ----
    lin_k<101, 26, 64, 64, 66, 104><<<NT, 256, 0, stream>>>(B2, wl_cls, bl_cls, y_cls);
    edge_cls_k<<<N2, 256, 0, stream>>>(y_cls, pos, rs, csrc, wl_cls, aggc);
    lin_k<101, 26, 101, 104, 101, 101><<<NT, 256, 0, stream>>>(aggc, wg_cls, bg_cls,
                                                               (float*)d_out);
    final_ro_k<<<NB, 256, 0, stream>>>(aggr, aggo, wg_reg, bg_reg, wg_obj, bg_obj,
                                       (float*)d_out);
}

// Round 3
// 1855.234 us; speedup vs baseline: 11.6222x; 1.1062x over previous
//
#include <hip/hip_runtime.h>

#define NN 100000
#define NE 1600000
#define NCLS 101
#define EPS_BN 1e-5f
#define NB_SCAN 391   // ceil(NN/256)
#define NINF (-__builtin_inff())

// ============================================================================
// CSR build: histogram -> block scan -> global scan -> scatter
// ============================================================================
__global__ __launch_bounds__(256) void hist_k(const int* __restrict__ dst,
                                              int* __restrict__ cnt) {
    int e = blockIdx.x * 256 + threadIdx.x;
    if (e < NE) atomicAdd(&cnt[dst[e]], 1);
}

__global__ __launch_bounds__(256) void scan1_k(const int* __restrict__ cnt,
                                               int* __restrict__ rs,
                                               int* __restrict__ blk) {
    __shared__ int sh[256];
    int t = threadIdx.x;
    int i = blockIdx.x * 256 + t;
    int v = (i < NN) ? cnt[i] : 0;
    sh[t] = v;
    __syncthreads();
    for (int off = 1; off < 256; off <<= 1) {
        int u = (t >= off) ? sh[t - off] : 0;
        __syncthreads();
        sh[t] += u;
        __syncthreads();
    }
    if (i < NN) rs[i] = sh[t] - v;
    if (t == 255) blk[blockIdx.x] = sh[255];
}

__global__ __launch_bounds__(512) void scan2_k(int* __restrict__ blk) {
    __shared__ int sh[512];
    int t = threadIdx.x;
    int v = (t < NB_SCAN) ? blk[t] : 0;
    sh[t] = v;
    __syncthreads();
    for (int off = 1; off < 512; off <<= 1) {
        int u = (t >= off) ? sh[t - off] : 0;
        __syncthreads();
        sh[t] += u;
        __syncthreads();
    }
    if (t < NB_SCAN) blk[t] = sh[t] - v;
}

__global__ __launch_bounds__(256) void scan3_k(int* __restrict__ rs,
                                               const int* __restrict__ blk,
                                               int* __restrict__ cur) {
    int i = blockIdx.x * 256 + threadIdx.x;
    if (i < NN) {
        int v = rs[i] + blk[i >> 8];
        rs[i] = v;
        cur[i] = v;
    } else if (i == NN) {
        rs[NN] = NE;
    }
}

__global__ __launch_bounds__(256) void scatter_k(const int* __restrict__ src,
                                                 const int* __restrict__ dst,
                                                 int* __restrict__ cur,
                                                 int* __restrict__ csrc) {
    int e = blockIdx.x * 256 + threadIdx.x;
    if (e >= NE) return;
    int d = dst[e];
    int p = atomicAdd(&cur[d], 1);
    csrc[p] = src[e];
}

__global__ __launch_bounds__(256) void pos2_k(const float* __restrict__ pos,
                                              float2* __restrict__ pos2) {
    int n = blockIdx.x * 256 + threadIdx.x;
    if (n < NN) pos2[n] = make_float2(pos[n * 3], pos[n * 3 + 1]);
}

// ============================================================================
// Node-side GEMM: out[n][(c)*ES] = sum_j in[n][j]*w[c][j] + b[c]
// 64-node tile in LDS [j][n] pad 65 (conflict-free); weights wave-uniform.
// ============================================================================
template <int COUT, int CPW, int K, int IS, int WS, int OS, int ES>
__global__ __launch_bounds__(256) void lin_k(const float* __restrict__ in,
                                             const float* __restrict__ w,
                                             const float* __restrict__ b,
                                             float* __restrict__ out) {
    __shared__ float xs[K * 65];
    int base = blockIdx.x * 64;
    for (int p = threadIdx.x; p < 64 * K; p += 256) {
        int n = p / K, j = p - n * K;
        xs[j * 65 + n] = (base + n < NN) ? in[(size_t)(base + n) * IS + j] : 0.f;
    }
    __syncthreads();
    int wid = threadIdx.x >> 6, lane = threadIdx.x & 63;
    int node = base + lane;
    int c0 = wid * CPW;
    float acc[CPW];
#pragma unroll
    for (int k = 0; k < CPW; ++k) acc[k] = (c0 + k < COUT) ? b[c0 + k] : 0.f;
    for (int j = 0; j < K; ++j) {
        float xv = xs[j * 65 + lane];
#pragma unroll
        for (int k = 0; k < CPW; ++k)
            acc[k] = fmaf(xv, (c0 + k < COUT) ? w[(size_t)(c0 + k) * WS + j] : 0.f,
                          acc[k]);
    }
    if (node < NN) {
#pragma unroll
        for (int k = 0; k < CPW; ++k)
            if (c0 + k < COUT) out[(size_t)node * OS + (size_t)(c0 + k) * ES] = acc[k];
    }
}

// ============================================================================
// Edge segment-max over CSR, unroll x4 for memory-level parallelism.
// ============================================================================
__global__ __launch_bounds__(256) void edge1_k(const float* __restrict__ y,   // stride 64
                                               const float2* __restrict__ pos2,
                                               const int* __restrict__ rs,
                                               const int* __restrict__ csrc,
                                               const float* __restrict__ wl,  // (64,66)
                                               float* __restrict__ agg) {
    int wid = threadIdx.x >> 6, lane = threadIdx.x & 63;
    int node = blockIdx.x * 4 + wid;
    if (node >= NN) return;
    float wp0 = wl[lane * 66 + 64], wp1 = wl[lane * 66 + 65];
    float2 pd = pos2[node];
    int i0 = rs[node], i1 = rs[node + 1];
    float acc = NINF;
    int i = i0;
    for (; i + 4 <= i1; i += 4) {
        int s0 = csrc[i + 0], s1 = csrc[i + 1], s2 = csrc[i + 2], s3 = csrc[i + 3];
        float2 p0 = pos2[s0], p1 = pos2[s1], p2 = pos2[s2], p3 = pos2[s3];
        float v0 = y[(size_t)s0 * 64 + lane];
        float v1 = y[(size_t)s1 * 64 + lane];
        float v2 = y[(size_t)s2 * 64 + lane];
        float v3 = y[(size_t)s3 * 64 + lane];
        v0 = fmaf(p0.y - pd.y, wp1, fmaf(p0.x - pd.x, wp0, v0));
        v1 = fmaf(p1.y - pd.y, wp1, fmaf(p1.x - pd.x, wp0, v1));
        v2 = fmaf(p2.y - pd.y, wp1, fmaf(p2.x - pd.x, wp0, v2));
        v3 = fmaf(p3.y - pd.y, wp1, fmaf(p3.x - pd.x, wp0, v3));
        acc = fmaxf(acc, fmaxf(fmaxf(v0, v1), fmaxf(v2, v3)));
    }
    for (; i < i1; ++i) {
        int s = csrc[i];
        float2 p = pos2[s];
        float v = fmaf(p.y - pd.y, wp1,
                       fmaf(p.x - pd.x, wp0, y[(size_t)s * 64 + lane]));
        acc = fmaxf(acc, v);
    }
    agg[(size_t)node * 64 + lane] = fmaxf(acc, 0.0f);
}

// y12 layout: [n][64][2] — float2 per channel = (c1 proj, c2 proj)
__global__ __launch_bounds__(256) void edge2_k(const float* __restrict__ y12,
                                               const float2* __restrict__ pos2,
                                               const int* __restrict__ rs,
                                               const int* __restrict__ csrc,
                                               const float* __restrict__ wlA,
                                               const float* __restrict__ wlB,
                                               float* __restrict__ a1,
                                               float* __restrict__ a2) {
    int wid = threadIdx.x >> 6, lane = threadIdx.x & 63;
    int node = blockIdx.x * 4 + wid;
    if (node >= NN) return;
    float wa0 = wlA[lane * 66 + 64], wa1 = wlA[lane * 66 + 65];
    float wb0 = wlB[lane * 66 + 64], wb1 = wlB[lane * 66 + 65];
    float2 pd = pos2[node];
    int i0 = rs[node], i1 = rs[node + 1];
    float accA = NINF, accB = NINF;
    int i = i0;
    for (; i + 4 <= i1; i += 4) {
        int s0 = csrc[i + 0], s1 = csrc[i + 1], s2 = csrc[i + 2], s3 = csrc[i + 3];
        float2 p0 = pos2[s0], p1 = pos2[s1], p2 = pos2[s2], p3 = pos2[s3];
        float2 v0 = *(const float2*)(y12 + (size_t)s0 * 128 + lane * 2);
        float2 v1 = *(const float2*)(y12 + (size_t)s1 * 128 + lane * 2);
        float2 v2 = *(const float2*)(y12 + (size_t)s2 * 128 + lane * 2);
        float2 v3 = *(const float2*)(y12 + (size_t)s3 * 128 + lane * 2);
        float dx0 = p0.x - pd.x, dy0 = p0.y - pd.y;
        float dx1 = p1.x - pd.x, dy1 = p1.y - pd.y;
        float dx2 = p2.x - pd.x, dy2 = p2.y - pd.y;
        float dx3 = p3.x - pd.x, dy3 = p3.y - pd.y;
        accA = fmaxf(accA, fmaxf(fmaxf(fmaf(dy0, wa1, fmaf(dx0, wa0, v0.x)),
                                       fmaf(dy1, wa1, fmaf(dx1, wa0, v1.x))),
                                 fmaxf(fmaf(dy2, wa1, fmaf(dx2, wa0, v2.x)),
                                       fmaf(dy3, wa1, fmaf(dx3, wa0, v3.x)))));
        accB = fmaxf(accB, fmaxf(fmaxf(fmaf(dy0, wb1, fmaf(dx0, wb0, v0.y)),
                                       fmaf(dy1, wb1, fmaf(dx1, wb0, v1.y))),
                                 fmaxf(fmaf(dy2, wb1, fmaf(dx2, wb0, v2.y)),
                                       fmaf(dy3, wb1, fmaf(dx3, wb0, v3.y)))));
    }
    for (; i < i1; ++i) {
        int s = csrc[i];
        float2 p = pos2[s];
        float2 v = *(const float2*)(y12 + (size_t)s * 128 + lane * 2);
        float dx = p.x - pd.x, dy = p.y - pd.y;
        accA = fmaxf(accA, fmaf(dy, wa1, fmaf(dx, wa0, v.x)));
        accB = fmaxf(accB, fmaf(dy, wb1, fmaf(dx, wb0, v.y)));
    }
    a1[(size_t)node * 64 + lane] = fmaxf(accA, 0.0f);
    a2[(size_t)node * 64 + lane] = fmaxf(accB, 0.0f);
}

__global__ __launch_bounds__(256) void edge_cls_k(const float* __restrict__ y,  // stride 104
                                                  const float2* __restrict__ pos2,
                                                  const int* __restrict__ rs,
                                                  const int* __restrict__ csrc,
                                                  const float* __restrict__ wl,  // (101,66)
                                                  float* __restrict__ agg) {     // stride 104
    int half = threadIdx.x >> 7;       // 2 nodes / block
    int t = threadIdx.x & 127;
    int node = blockIdx.x * 2 + half;
    if (node >= NN) return;
    int tc = (t < NCLS) ? t : (NCLS - 1);   // clamp: inactive lanes duplicate c=100
    float wp0 = wl[tc * 66 + 64], wp1 = wl[tc * 66 + 65];
    float2 pd = pos2[node];
    int i0 = rs[node], i1 = rs[node + 1];
    float acc = NINF;
    int i = i0;
    for (; i + 4 <= i1; i += 4) {
        int s0 = csrc[i + 0], s1 = csrc[i + 1], s2 = csrc[i + 2], s3 = csrc[i + 3];
        float2 p0 = pos2[s0], p1 = pos2[s1], p2 = pos2[s2], p3 = pos2[s3];
        float v0 = y[(size_t)s0 * 104 + tc];
        float v1 = y[(size_t)s1 * 104 + tc];
        float v2 = y[(size_t)s2 * 104 + tc];
        float v3 = y[(size_t)s3 * 104 + tc];
        v0 = fmaf(p0.y - pd.y, wp1, fmaf(p0.x - pd.x, wp0, v0));
        v1 = fmaf(p1.y - pd.y, wp1, fmaf(p1.x - pd.x, wp0, v1));
        v2 = fmaf(p2.y - pd.y, wp1, fmaf(p2.x - pd.x, wp0, v2));
        v3 = fmaf(p3.y - pd.y, wp1, fmaf(p3.x - pd.x, wp0, v3));
        acc = fmaxf(acc, fmaxf(fmaxf(v0, v1), fmaxf(v2, v3)));
    }
    for (; i < i1; ++i) {
        int s = csrc[i];
        float2 p = pos2[s];
        float v = fmaf(p.y - pd.y, wp1,
                       fmaf(p.x - pd.x, wp0, y[(size_t)s * 104 + tc]));
        acc = fmaxf(acc, v);
    }
    if (t < NCLS) agg[(size_t)node * 104 + t] = fmaxf(acc, 0.0f);
}

// reg+obj: 5 channels packed stride 8; wave = 8 edge-slots x 8 channel-slots
__global__ __launch_bounds__(256) void edge_ro_k(const float* __restrict__ y,  // stride 8
                                                 const float2* __restrict__ pos2,
                                                 const int* __restrict__ rs,
                                                 const int* __restrict__ csrc,
                                                 const float* __restrict__ wro,  // (5,66)
                                                 float* __restrict__ aggr,
                                                 float* __restrict__ aggo) {
    int wid = threadIdx.x >> 6, lane = threadIdx.x & 63;
    int node = blockIdx.x * 4 + wid;
    if (node >= NN) return;
    int k = lane >> 3, c = lane & 7;
    int cc = (c < 5) ? c : 4;
    float wp0 = wro[cc * 66 + 64], wp1 = wro[cc * 66 + 65];
    float2 pd = pos2[node];
    int i0 = rs[node], i1 = rs[node + 1];
    float acc = NINF;
    for (int i = i0 + k; i < i1; i += 8) {
        int s = csrc[i];
        float2 p = pos2[s];
        float v = y[(size_t)s * 8 + cc];
        acc = fmaxf(acc, fmaf(p.y - pd.y, wp1, fmaf(p.x - pd.x, wp0, v)));
    }
    acc = fmaxf(acc, __shfl_xor(acc, 8, 64));
    acc = fmaxf(acc, __shfl_xor(acc, 16, 64));
    acc = fmaxf(acc, __shfl_xor(acc, 32, 64));
    acc = fmaxf(acc, 0.0f);
    if (lane < 5) {
        if (lane < 4) aggr[(size_t)node * 4 + lane] = acc;
        else          aggo[node] = acc;
    }
}

// ============================================================================
// BN: column sums -> params -> apply
// ============================================================================
__global__ __launch_bounds__(256) void stats_k(const float* __restrict__ x,
                                               float* __restrict__ st) {
    __shared__ float sS[4][64], sQ[4][64];
    int wid = threadIdx.x >> 6, lane = threadIdx.x & 63;
    float s = 0.f, q = 0.f;
    for (int n = blockIdx.x * 4 + wid; n < NN; n += 512) {
        float v = x[(size_t)n * 64 + lane];
        s += v;
        q = fmaf(v, v, q);
    }
    sS[wid][lane] = s;
    sQ[wid][lane] = q;
    __syncthreads();
    if (wid == 0) {
        float ts = sS[0][lane] + sS[1][lane] + sS[2][lane] + sS[3][lane];
        float tq = sQ[0][lane] + sQ[1][lane] + sQ[2][lane] + sQ[3][lane];
        atomicAdd(&st[lane], ts);
        atomicAdd(&st[64 + lane], tq);
    }
}

__global__ void bnpar_k(float* __restrict__ st, const float* __restrict__ g,
                        const float* __restrict__ b) {
    int c = threadIdx.x;
    if (c >= 64) return;
    float mu = st[c] * (1.0f / NN);
    float var = st[64 + c] * (1.0f / NN) - mu * mu;
    float sc = g[c] * rsqrtf(var + EPS_BN);
    st[128 + c] = sc;
    st[192 + c] = b[c] - mu * sc;
}

__global__ __launch_bounds__(256) void bnrelu_k(float* __restrict__ x,
                                                const float* __restrict__ st) {
    int i = blockIdx.x * 256 + threadIdx.x;   // over NN*16 float4s
    if (i >= NN * 16) return;
    float4 v = ((float4*)x)[i];
    int c0 = (i * 4) & 63;
    v.x = fmaxf(fmaf(v.x, st[128 + c0 + 0], st[192 + c0 + 0]), 0.f);
    v.y = fmaxf(fmaf(v.y, st[128 + c0 + 1], st[192 + c0 + 1]), 0.f);
    v.z = fmaxf(fmaf(v.z, st[128 + c0 + 2], st[192 + c0 + 2]), 0.f);
    v.w = fmaxf(fmaf(v.w, st[128 + c0 + 3], st[192 + c0 + 3]), 0.f);
    ((float4*)x)[i] = v;
}

__global__ void pack_ro_k(const float* __restrict__ wlr, const float* __restrict__ blr,
                          const float* __restrict__ wlo, const float* __restrict__ blo,
                          float* __restrict__ wro, float* __restrict__ bro) {
    int t = threadIdx.x;
    if (t < 5 * 66) {
        int cc = t / 66, j = t - cc * 66;
        wro[t] = (cc < 4) ? wlr[t] : wlo[j];
    }
    if (t < 5) bro[t] = (t < 4) ? blr[t] : blo[0];
}

__global__ __launch_bounds__(256) void final_ro_k(const float* __restrict__ aggr,
                                                  const float* __restrict__ aggo,
                                                  const float* __restrict__ wgr,
                                                  const float* __restrict__ bgr,
                                                  const float* __restrict__ wgo,
                                                  const float* __restrict__ bgo,
                                                  float* __restrict__ out) {
    int n = blockIdx.x * 256 + threadIdx.x;
    if (n >= NN) return;
    float a0 = aggr[(size_t)n * 4 + 0], a1 = aggr[(size_t)n * 4 + 1];
    float a2 = aggr[(size_t)n * 4 + 2], a3 = aggr[(size_t)n * 4 + 3];
    float* reg = out + (size_t)NN * NCLS;
    float* obj = reg + (size_t)NN * 4;
#pragma unroll
    for (int k = 0; k < 4; ++k) {
        float acc = bgr[k];
        acc = fmaf(a0, wgr[k * 4 + 0], acc);
        acc = fmaf(a1, wgr[k * 4 + 1], acc);
        acc = fmaf(a2, wgr[k * 4 + 2], acc);
        acc = fmaf(a3, wgr[k * 4 + 3], acc);
        reg[(size_t)n * 4 + k] = acc;
    }
    obj[n] = fmaf(aggo[n], wgo[0], bgo[0]);
}

// ============================================================================
extern "C" void kernel_launch(void* const* d_in, const int* in_sizes, int n_in,
                              void* d_out, int out_size, void* d_ws, size_t ws_size,
                              hipStream_t stream) {
    const float* x   = (const float*)d_in[0];
    const float* pos = (const float*)d_in[1];
    const int* ei    = (const int*)d_in[2];
    const int* src = ei;
    const int* dst = ei + NE;
    const float* wl_stem = (const float*)d_in[3];
    const float* bl_stem = (const float*)d_in[4];
    const float* wg_stem = (const float*)d_in[5];
    const float* bg_stem = (const float*)d_in[6];
    const float* g_stem  = (const float*)d_in[7];
    const float* b_stem  = (const float*)d_in[8];
    const float* wl_c1 = (const float*)d_in[9];
    const float* bl_c1 = (const float*)d_in[10];
    const float* wg_c1 = (const float*)d_in[11];
    const float* bg_c1 = (const float*)d_in[12];
    const float* g_c1  = (const float*)d_in[13];
    const float* b_c1  = (const float*)d_in[14];
    const float* wl_c2 = (const float*)d_in[15];
    const float* bl_c2 = (const float*)d_in[16];
    const float* wg_c2 = (const float*)d_in[17];
    const float* bg_c2 = (const float*)d_in[18];
    const float* g_c2  = (const float*)d_in[19];
    const float* b_c2  = (const float*)d_in[20];
    const float* wl_reg = (const float*)d_in[21];
    const float* bl_reg = (const float*)d_in[22];
    const float* wg_reg = (const float*)d_in[23];
    const float* bg_reg = (const float*)d_in[24];
    const float* wl_cls = (const float*)d_in[25];
    const float* bl_cls = (const float*)d_in[26];
    const float* wg_cls = (const float*)d_in[27];
    const float* bg_cls = (const float*)d_in[28];
    const float* wl_obj = (const float*)d_in[29];
    const float* bl_obj = (const float*)d_in[30];
    const float* wg_obj = (const float*)d_in[31];
    const float* bg_obj = (const float*)d_in[32];

    float* ws = (float*)d_ws;
    // Arena (contiguous): S0[N*128] | S1[N*64] | S2[N*64] | S3[N*64] | ints/smalls
    // Lifetimes: S0: y12 -> y_cls(104).  S1: y_stem -> a1/x1 -> aggc(104, spans S1+S2).
    //            S2: agg_stem/h.         S3: a2/x2.
    float* S0 = ws;
    float* S1 = S0 + (size_t)NN * 128;
    float* S2 = S1 + (size_t)NN * 64;
    float* S3 = S2 + (size_t)NN * 64;
    float* y12   = S0;
    float* y_cls = S0;
    float* aggc  = S1;     // N*104 spans S1+S2 (both dead by then)
    int*   rs   = (int*)(S3 + (size_t)NN * 64);   // NN+1 (padded)
    int*   cnt  = rs + 100016;
    int*   csrc = cnt + 100016;                   // NE
    float* pos2 = (float*)(csrc + NE);            // NN float2
    float* y_ro = pos2 + (size_t)NN * 2;          // NN*8
    float* aggr = y_ro + (size_t)NN * 8;          // NN*4
    float* aggo = aggr + (size_t)NN * 4;          // NN
    float* st   = aggo + NN;                      // 3*256
    float* st0 = st, *st1 = st + 256, *st2 = st + 512;
    float* wro = st + 768;                        // 5*66
    float* bro = wro + 336;
    int*   blk = (int*)(bro + 16);                // scan block sums

    hipMemsetAsync(cnt, 0, 100016 * sizeof(int), stream);
    hipMemsetAsync(st, 0, 768 * sizeof(float), stream);

    const int EB = (NE + 255) / 256;      // 6250
    const int NB = (NN + 255) / 256;      // 391
    const int N4 = (NN + 3) / 4;          // 25000
    const int N2 = (NN + 1) / 2;          // 50000
    const int NT = (NN + 63) / 64;        // 1563
    const int XB = NN * 16 / 256;         // 6250

    // ---- CSR build + pos2 ----
    pos2_k<<<NB, 256, 0, stream>>>(pos, (float2*)pos2);
    hist_k<<<EB, 256, 0, stream>>>(dst, cnt);
    scan1_k<<<NB_SCAN, 256, 0, stream>>>(cnt, rs, blk);
    scan2_k<<<1, 512, 0, stream>>>(blk);
    scan3_k<<<NB + 1, 256, 0, stream>>>(rs, blk, cnt);
    scatter_k<<<EB, 256, 0, stream>>>(src, dst, cnt, csrc);

    // ---- stem ----
    lin_k<64, 16, 64, 64, 66, 64, 1><<<NT, 256, 0, stream>>>(x, wl_stem, bl_stem, S1);
    edge1_k<<<N4, 256, 0, stream>>>(S1, (float2*)pos2, rs, csrc, wl_stem, S2);
    lin_k<64, 16, 64, 64, 64, 64, 1><<<NT, 256, 0, stream>>>(S2, wg_stem, bg_stem, S2);
    stats_k<<<128, 256, 0, stream>>>(S2, st0);
    bnpar_k<<<1, 64, 0, stream>>>(st0, g_stem, b_stem);
    bnrelu_k<<<XB, 256, 0, stream>>>(S2, st0);

    // ---- c1 + c2 (shared edge pass, interleaved y12) ----
    lin_k<64, 16, 64, 64, 66, 128, 2><<<NT, 256, 0, stream>>>(S2, wl_c1, bl_c1, y12);
    lin_k<64, 16, 64, 64, 66, 128, 2><<<NT, 256, 0, stream>>>(S2, wl_c2, bl_c2, y12 + 1);
    edge2_k<<<N4, 256, 0, stream>>>(y12, (float2*)pos2, rs, csrc, wl_c1, wl_c2, S1, S3);
    lin_k<64, 16, 64, 64, 64, 64, 1><<<NT, 256, 0, stream>>>(S1, wg_c1, bg_c1, S1);
    stats_k<<<128, 256, 0, stream>>>(S1, st1);
    bnpar_k<<<1, 64, 0, stream>>>(st1, g_c1, b_c1);
    bnrelu_k<<<XB, 256, 0, stream>>>(S1, st1);
    lin_k<64, 16, 64, 64, 64, 64, 1><<<NT, 256, 0, stream>>>(S3, wg_c2, bg_c2, S3);
    stats_k<<<128, 256, 0, stream>>>(S3, st2);
    bnpar_k<<<1, 64, 0, stream>>>(st2, g_c2, b_c2);
    bnrelu_k<<<XB, 256, 0, stream>>>(S3, st2);

    // ---- reg + obj heads (input x1 = S1) ----
    pack_ro_k<<<1, 512, 0, stream>>>(wl_reg, bl_reg, wl_obj, bl_obj, wro, bro);
    lin_k<5, 2, 64, 64, 66, 8, 1><<<NT, 256, 0, stream>>>(S1, wro, bro, y_ro);
    edge_ro_k<<<N4, 256, 0, stream>>>(y_ro, (float2*)pos2, rs, csrc, wro, aggr, aggo);

    // ---- cls head (input x2 = S3) ----
    lin_k<101, 26, 64, 64, 66, 104, 1><<<NT, 256, 0, stream>>>(S3, wl_cls, bl_cls, y_cls);
    edge_cls_k<<<N2, 256, 0, stream>>>(y_cls, (float2*)pos2, rs, csrc, wl_cls, aggc);
    lin_k<101, 26, 101, 104, 101, 101, 1><<<NT, 256, 0, stream>>>(aggc, wg_cls, bg_cls,
                                                                  (float*)d_out);
    final_ro_k<<<NB, 256, 0, stream>>>(aggr, aggo, wg_reg, bg_reg, wg_obj, bg_obj,
                                       (float*)d_out);
}

// Round 4
// 1441.682 us; speedup vs baseline: 14.9561x; 1.2869x over previous
//
#include <hip/hip_runtime.h>

#define NN 100000
#define NE 1600000
#define NCLS 101
#define EPS_BN 1e-5f
#define NB_SCAN 391   // ceil(NN/256)
#define NINF (-__builtin_inff())

__device__ __forceinline__ int rl_i(int v, int j) {
    return __builtin_amdgcn_readlane(v, j);
}
__device__ __forceinline__ float rl_f(float v, int j) {
    return __int_as_float(__builtin_amdgcn_readlane(__float_as_int(v), j));
}

// ============================================================================
// CSR build: histogram -> block scan -> global scan -> scatter
// ============================================================================
__global__ __launch_bounds__(256) void hist_k(const int* __restrict__ dst,
                                              int* __restrict__ cnt) {
    int e = blockIdx.x * 256 + threadIdx.x;
    if (e < NE) atomicAdd(&cnt[dst[e]], 1);
}

__global__ __launch_bounds__(256) void scan1_k(const int* __restrict__ cnt,
                                               int* __restrict__ rs,
                                               int* __restrict__ blk) {
    __shared__ int sh[256];
    int t = threadIdx.x;
    int i = blockIdx.x * 256 + t;
    int v = (i < NN) ? cnt[i] : 0;
    sh[t] = v;
    __syncthreads();
    for (int off = 1; off < 256; off <<= 1) {
        int u = (t >= off) ? sh[t - off] : 0;
        __syncthreads();
        sh[t] += u;
        __syncthreads();
    }
    if (i < NN) rs[i] = sh[t] - v;
    if (t == 255) blk[blockIdx.x] = sh[255];
}

__global__ __launch_bounds__(512) void scan2_k(int* __restrict__ blk) {
    __shared__ int sh[512];
    int t = threadIdx.x;
    int v = (t < NB_SCAN) ? blk[t] : 0;
    sh[t] = v;
    __syncthreads();
    for (int off = 1; off < 512; off <<= 1) {
        int u = (t >= off) ? sh[t - off] : 0;
        __syncthreads();
        sh[t] += u;
        __syncthreads();
    }
    if (t < NB_SCAN) blk[t] = sh[t] - v;
}

__global__ __launch_bounds__(256) void scan3_k(int* __restrict__ rs,
                                               const int* __restrict__ blk,
                                               int* __restrict__ cur) {
    int i = blockIdx.x * 256 + threadIdx.x;
    if (i < NN) {
        int v = rs[i] + blk[i >> 8];
        rs[i] = v;
        cur[i] = v;
    } else if (i == NN) {
        rs[NN] = NE;
    }
}

__global__ __launch_bounds__(256) void scatter_k(const int* __restrict__ src,
                                                 const int* __restrict__ dst,
                                                 int* __restrict__ cur,
                                                 int* __restrict__ csrc) {
    int e = blockIdx.x * 256 + threadIdx.x;
    if (e >= NE) return;
    int d = dst[e];
    int p = atomicAdd(&cur[d], 1);
    csrc[p] = src[e];
}

__global__ __launch_bounds__(256) void pos2_k(const float* __restrict__ pos,
                                              float2* __restrict__ pos2) {
    int n = blockIdx.x * 256 + threadIdx.x;
    if (n < NN) pos2[n] = make_float2(pos[n * 3], pos[n * 3 + 1]);
}

// ============================================================================
// Node-side GEMM: out[n][c*ES] = sum_j in[n][j]*w[c][j] + b[c]
// 64-node tile in LDS [j][n] pad 65. Weight rows are forced wave-uniform via
// readfirstlane -> s_load + v_fmac with SGPR operand (VMEM stays idle).
// ============================================================================
template <int COUT, int CPW, int K, int IS, int WS, int OS, int ES>
__global__ __launch_bounds__(256) void lin_k(const float* __restrict__ in,
                                             const float* __restrict__ w,
                                             const float* __restrict__ b,
                                             float* __restrict__ out) {
    __shared__ float xs[K * 65];
    int base = blockIdx.x * 64;
    for (int p = threadIdx.x; p < 64 * K; p += 256) {
        int n = p / K, j = p - n * K;
        xs[j * 65 + n] = (base + n < NN) ? in[(size_t)(base + n) * IS + j] : 0.f;
    }
    __syncthreads();
    int wid = __builtin_amdgcn_readfirstlane(threadIdx.x >> 6);
    int lane = threadIdx.x & 63;
    int node = base + lane;
    int c0 = wid * CPW;
    int coff[CPW];     // SGPR weight-row offsets (clamped -> always in bounds)
    float acc[CPW];
#pragma unroll
    for (int k = 0; k < CPW; ++k) {
        int c = (c0 + k < COUT) ? (c0 + k) : (COUT - 1);
        coff[k] = c * WS;
        acc[k] = b[c];
    }
    for (int j = 0; j < K; ++j) {
        float xv = xs[j * 65 + lane];
#pragma unroll
        for (int k = 0; k < CPW; ++k)
            acc[k] = fmaf(xv, w[coff[k] + j], acc[k]);
    }
    if (node < NN) {
#pragma unroll
        for (int k = 0; k < CPW; ++k)
            if (c0 + k < COUT) out[(size_t)node * OS + (size_t)(c0 + k) * ES] = acc[k];
    }
}

// Fused c1+c2 projection (shared input, one LDS staging), writes y12 [n][64]{f2}
__global__ __launch_bounds__(256) void lin2_k(const float* __restrict__ in,
                                              const float* __restrict__ wA,
                                              const float* __restrict__ bA,
                                              const float* __restrict__ wB,
                                              const float* __restrict__ bB,
                                              float2* __restrict__ out) {
    __shared__ float xs[64 * 65];
    int base = blockIdx.x * 64;
    for (int p = threadIdx.x; p < 64 * 64; p += 256) {
        int n = p >> 6, j = p & 63;
        xs[j * 65 + n] = (base + n < NN) ? in[(size_t)(base + n) * 64 + j] : 0.f;
    }
    __syncthreads();
    int wid = __builtin_amdgcn_readfirstlane(threadIdx.x >> 6);
    int lane = threadIdx.x & 63;
    int node = base + lane;
    int c0 = wid * 16;
    float accA[16], accB[16];
#pragma unroll
    for (int k = 0; k < 16; ++k) {
        accA[k] = bA[c0 + k];
        accB[k] = bB[c0 + k];
    }
    for (int j = 0; j < 64; ++j) {
        float xv = xs[j * 65 + lane];
#pragma unroll
        for (int k = 0; k < 16; ++k) {
            accA[k] = fmaf(xv, wA[(c0 + k) * 66 + j], accA[k]);
            accB[k] = fmaf(xv, wB[(c0 + k) * 66 + j], accB[k]);
        }
    }
    if (node < NN) {
#pragma unroll
        for (int k = 0; k < 16; ++k)
            out[(size_t)node * 64 + c0 + k] = make_float2(accA[k], accB[k]);
    }
}

// ============================================================================
// Edge segment-max over CSR. Wave per node, lane = channel. Edge indices and
// pos2 are loaded coalesced once per 64-edge batch, then broadcast per edge
// via v_readlane -> the per-edge row gather uses an SGPR base address.
// ============================================================================
__global__ __launch_bounds__(256) void edge1_k(const float* __restrict__ y,   // stride 64
                                               const float2* __restrict__ pos2,
                                               const int* __restrict__ rs,
                                               const int* __restrict__ csrc,
                                               const float* __restrict__ wl,  // (64,66)
                                               float* __restrict__ agg) {
    int wid = __builtin_amdgcn_readfirstlane(threadIdx.x >> 6);
    int lane = threadIdx.x & 63;
    int node = blockIdx.x * 4 + wid;
    if (node >= NN) return;
    float wp0 = wl[lane * 66 + 64], wp1 = wl[lane * 66 + 65];
    float2 pd = pos2[node];
    int i0 = rs[node], i1 = rs[node + 1];
    float acc = NINF;
    for (int ib = i0; ib < i1; ib += 64) {
        int m = i1 - ib;
        if (m > 64) m = 64;
        int t = ib + lane;
        int idx = (t < i1) ? csrc[t] : 0;
        float2 pp = pos2[idx];
        float ppx = pp.x, ppy = pp.y;
        int j = 0;
        for (; j + 4 <= m; j += 4) {
            int s0 = rl_i(idx, j + 0), s1 = rl_i(idx, j + 1);
            int s2 = rl_i(idx, j + 2), s3 = rl_i(idx, j + 3);
            float v0 = y[(size_t)s0 * 64 + lane];
            float v1 = y[(size_t)s1 * 64 + lane];
            float v2 = y[(size_t)s2 * 64 + lane];
            float v3 = y[(size_t)s3 * 64 + lane];
            v0 = fmaf(rl_f(ppy, j + 0) - pd.y, wp1, fmaf(rl_f(ppx, j + 0) - pd.x, wp0, v0));
            v1 = fmaf(rl_f(ppy, j + 1) - pd.y, wp1, fmaf(rl_f(ppx, j + 1) - pd.x, wp0, v1));
            v2 = fmaf(rl_f(ppy, j + 2) - pd.y, wp1, fmaf(rl_f(ppx, j + 2) - pd.x, wp0, v2));
            v3 = fmaf(rl_f(ppy, j + 3) - pd.y, wp1, fmaf(rl_f(ppx, j + 3) - pd.x, wp0, v3));
            acc = fmaxf(acc, fmaxf(fmaxf(v0, v1), fmaxf(v2, v3)));
        }
        for (; j < m; ++j) {
            int s = rl_i(idx, j);
            float v = y[(size_t)s * 64 + lane];
            v = fmaf(rl_f(ppy, j) - pd.y, wp1, fmaf(rl_f(ppx, j) - pd.x, wp0, v));
            acc = fmaxf(acc, v);
        }
    }
    agg[(size_t)node * 64 + lane] = fmaxf(acc, 0.0f);
}

// y12 layout: [n][64]{float2} = (c1 proj, c2 proj)
__global__ __launch_bounds__(256) void edge2_k(const float2* __restrict__ y12,
                                               const float2* __restrict__ pos2,
                                               const int* __restrict__ rs,
                                               const int* __restrict__ csrc,
                                               const float* __restrict__ wlA,
                                               const float* __restrict__ wlB,
                                               float* __restrict__ a1,
                                               float* __restrict__ a2) {
    int wid = __builtin_amdgcn_readfirstlane(threadIdx.x >> 6);
    int lane = threadIdx.x & 63;
    int node = blockIdx.x * 4 + wid;
    if (node >= NN) return;
    float wa0 = wlA[lane * 66 + 64], wa1 = wlA[lane * 66 + 65];
    float wb0 = wlB[lane * 66 + 64], wb1 = wlB[lane * 66 + 65];
    float2 pd = pos2[node];
    int i0 = rs[node], i1 = rs[node + 1];
    float accA = NINF, accB = NINF;
    for (int ib = i0; ib < i1; ib += 64) {
        int m = i1 - ib;
        if (m > 64) m = 64;
        int t = ib + lane;
        int idx = (t < i1) ? csrc[t] : 0;
        float2 pp = pos2[idx];
        float ppx = pp.x, ppy = pp.y;
        int j = 0;
        for (; j + 4 <= m; j += 4) {
            int s0 = rl_i(idx, j + 0), s1 = rl_i(idx, j + 1);
            int s2 = rl_i(idx, j + 2), s3 = rl_i(idx, j + 3);
            float2 v0 = y12[(size_t)s0 * 64 + lane];
            float2 v1 = y12[(size_t)s1 * 64 + lane];
            float2 v2 = y12[(size_t)s2 * 64 + lane];
            float2 v3 = y12[(size_t)s3 * 64 + lane];
            float dx0 = rl_f(ppx, j + 0) - pd.x, dy0 = rl_f(ppy, j + 0) - pd.y;
            float dx1 = rl_f(ppx, j + 1) - pd.x, dy1 = rl_f(ppy, j + 1) - pd.y;
            float dx2 = rl_f(ppx, j + 2) - pd.x, dy2 = rl_f(ppy, j + 2) - pd.y;
            float dx3 = rl_f(ppx, j + 3) - pd.x, dy3 = rl_f(ppy, j + 3) - pd.y;
            accA = fmaxf(accA, fmaxf(fmaxf(fmaf(dy0, wa1, fmaf(dx0, wa0, v0.x)),
                                           fmaf(dy1, wa1, fmaf(dx1, wa0, v1.x))),
                                     fmaxf(fmaf(dy2, wa1, fmaf(dx2, wa0, v2.x)),
                                           fmaf(dy3, wa1, fmaf(dx3, wa0, v3.x)))));
            accB = fmaxf(accB, fmaxf(fmaxf(fmaf(dy0, wb1, fmaf(dx0, wb0, v0.y)),
                                           fmaf(dy1, wb1, fmaf(dx1, wb0, v1.y))),
                                     fmaxf(fmaf(dy2, wb1, fmaf(dx2, wb0, v2.y)),
                                           fmaf(dy3, wb1, fmaf(dx3, wb0, v3.y)))));
        }
        for (; j < m; ++j) {
            int s = rl_i(idx, j);
            float2 v = y12[(size_t)s * 64 + lane];
            float dx = rl_f(ppx, j) - pd.x, dy = rl_f(ppy, j) - pd.y;
            accA = fmaxf(accA, fmaf(dy, wa1, fmaf(dx, wa0, v.x)));
            accB = fmaxf(accB, fmaf(dy, wb1, fmaf(dx, wb0, v.y)));
        }
    }
    a1[(size_t)node * 64 + lane] = fmaxf(accA, 0.0f);
    a2[(size_t)node * 64 + lane] = fmaxf(accB, 0.0f);
}

// cls: wave per node, lane covers channels {lane, lane+64 (clamped)}
__global__ __launch_bounds__(256) void edge_cls_k(const float* __restrict__ y,  // stride 104
                                                  const float2* __restrict__ pos2,
                                                  const int* __restrict__ rs,
                                                  const int* __restrict__ csrc,
                                                  const float* __restrict__ wl,  // (101,66)
                                                  float* __restrict__ agg) {     // stride 104
    int wid = __builtin_amdgcn_readfirstlane(threadIdx.x >> 6);
    int lane = threadIdx.x & 63;
    int node = blockIdx.x * 4 + wid;
    if (node >= NN) return;
    int chi = (lane + 64 < NCLS) ? (lane + 64) : (NCLS - 1);
    float wa0 = wl[lane * 66 + 64], wa1 = wl[lane * 66 + 65];
    float wb0 = wl[chi * 66 + 64], wb1 = wl[chi * 66 + 65];
    float2 pd = pos2[node];
    int i0 = rs[node], i1 = rs[node + 1];
    float accA = NINF, accB = NINF;
    for (int ib = i0; ib < i1; ib += 64) {
        int m = i1 - ib;
        if (m > 64) m = 64;
        int t = ib + lane;
        int idx = (t < i1) ? csrc[t] : 0;
        float2 pp = pos2[idx];
        float ppx = pp.x, ppy = pp.y;
        int j = 0;
        for (; j + 2 <= m; j += 2) {
            int s0 = rl_i(idx, j + 0), s1 = rl_i(idx, j + 1);
            float va0 = y[(size_t)s0 * 104 + lane];
            float vb0 = y[(size_t)s0 * 104 + chi];
            float va1 = y[(size_t)s1 * 104 + lane];
            float vb1 = y[(size_t)s1 * 104 + chi];
            float dx0 = rl_f(ppx, j + 0) - pd.x, dy0 = rl_f(ppy, j + 0) - pd.y;
            float dx1 = rl_f(ppx, j + 1) - pd.x, dy1 = rl_f(ppy, j + 1) - pd.y;
            accA = fmaxf(accA, fmaxf(fmaf(dy0, wa1, fmaf(dx0, wa0, va0)),
                                     fmaf(dy1, wa1, fmaf(dx1, wa0, va1))));
            accB = fmaxf(accB, fmaxf(fmaf(dy0, wb1, fmaf(dx0, wb0, vb0)),
                                     fmaf(dy1, wb1, fmaf(dx1, wb0, vb1))));
        }
        for (; j < m; ++j) {
            int s = rl_i(idx, j);
            float va = y[(size_t)s * 104 + lane];
            float vb = y[(size_t)s * 104 + chi];
            float dx = rl_f(ppx, j) - pd.x, dy = rl_f(ppy, j) - pd.y;
            accA = fmaxf(accA, fmaf(dy, wa1, fmaf(dx, wa0, va)));
            accB = fmaxf(accB, fmaf(dy, wb1, fmaf(dx, wb0, vb)));
        }
    }
    agg[(size_t)node * 104 + lane] = fmaxf(accA, 0.0f);
    if (lane + 64 < NCLS) agg[(size_t)node * 104 + 64 + lane] = fmaxf(accB, 0.0f);
}

// reg+obj: 5 channels packed stride 8; wave = 8 edge-slots x 8 channel-slots
__global__ __launch_bounds__(256) void edge_ro_k(const float* __restrict__ y,  // stride 8
                                                 const float2* __restrict__ pos2,
                                                 const int* __restrict__ rs,
                                                 const int* __restrict__ csrc,
                                                 const float* __restrict__ wro,  // (5,66)
                                                 float* __restrict__ aggr,
                                                 float* __restrict__ aggo) {
    int wid = __builtin_amdgcn_readfirstlane(threadIdx.x >> 6);
    int lane = threadIdx.x & 63;
    int node = blockIdx.x * 4 + wid;
    if (node >= NN) return;
    int k = lane >> 3, c = lane & 7;
    int cc = (c < 5) ? c : 4;
    float wp0 = wro[cc * 66 + 64], wp1 = wro[cc * 66 + 65];
    float2 pd = pos2[node];
    int i0 = rs[node], i1 = rs[node + 1];
    float acc = NINF;
    for (int i = i0 + k; i < i1; i += 8) {
        int s = csrc[i];
        float2 p = pos2[s];
        float v = y[(size_t)s * 8 + cc];
        acc = fmaxf(acc, fmaf(p.y - pd.y, wp1, fmaf(p.x - pd.x, wp0, v)));
    }
    acc = fmaxf(acc, __shfl_xor(acc, 8, 64));
    acc = fmaxf(acc, __shfl_xor(acc, 16, 64));
    acc = fmaxf(acc, __shfl_xor(acc, 32, 64));
    acc = fmaxf(acc, 0.0f);
    if (lane < 5) {
        if (lane < 4) aggr[(size_t)node * 4 + lane] = acc;
        else          aggo[node] = acc;
    }
}

// ============================================================================
// BN: column sums -> params -> apply
// ============================================================================
__global__ __launch_bounds__(256) void stats_k(const float* __restrict__ x,
                                               float* __restrict__ st) {
    __shared__ float sS[4][64], sQ[4][64];
    int wid = threadIdx.x >> 6, lane = threadIdx.x & 63;
    float s = 0.f, q = 0.f;
    for (int n = blockIdx.x * 4 + wid; n < NN; n += 512) {
        float v = x[(size_t)n * 64 + lane];
        s += v;
        q = fmaf(v, v, q);
    }
    sS[wid][lane] = s;
    sQ[wid][lane] = q;
    __syncthreads();
    if (wid == 0) {
        float ts = sS[0][lane] + sS[1][lane] + sS[2][lane] + sS[3][lane];
        float tq = sQ[0][lane] + sQ[1][lane] + sQ[2][lane] + sQ[3][lane];
        atomicAdd(&st[lane], ts);
        atomicAdd(&st[64 + lane], tq);
    }
}

__global__ void bnpar_k(float* __restrict__ st, const float* __restrict__ g,
                        const float* __restrict__ b) {
    int c = threadIdx.x;
    if (c >= 64) return;
    float mu = st[c] * (1.0f / NN);
    float var = st[64 + c] * (1.0f / NN) - mu * mu;
    float sc = g[c] * rsqrtf(var + EPS_BN);
    st[128 + c] = sc;
    st[192 + c] = b[c] - mu * sc;
}

__global__ __launch_bounds__(256) void bnrelu_k(float* __restrict__ x,
                                                const float* __restrict__ st) {
    int i = blockIdx.x * 256 + threadIdx.x;   // over NN*16 float4s
    if (i >= NN * 16) return;
    float4 v = ((float4*)x)[i];
    int c0 = (i * 4) & 63;
    v.x = fmaxf(fmaf(v.x, st[128 + c0 + 0], st[192 + c0 + 0]), 0.f);
    v.y = fmaxf(fmaf(v.y, st[128 + c0 + 1], st[192 + c0 + 1]), 0.f);
    v.z = fmaxf(fmaf(v.z, st[128 + c0 + 2], st[192 + c0 + 2]), 0.f);
    v.w = fmaxf(fmaf(v.w, st[128 + c0 + 3], st[192 + c0 + 3]), 0.f);
    ((float4*)x)[i] = v;
}

__global__ void pack_ro_k(const float* __restrict__ wlr, const float* __restrict__ blr,
                          const float* __restrict__ wlo, const float* __restrict__ blo,
                          float* __restrict__ wro, float* __restrict__ bro) {
    int t = threadIdx.x;
    if (t < 5 * 66) {
        int cc = t / 66, j = t - cc * 66;
        wro[t] = (cc < 4) ? wlr[t] : wlo[j];
    }
    if (t < 5) bro[t] = (t < 4) ? blr[t] : blo[0];
}

__global__ __launch_bounds__(256) void final_ro_k(const float* __restrict__ aggr,
                                                  const float* __restrict__ aggo,
                                                  const float* __restrict__ wgr,
                                                  const float* __restrict__ bgr,
                                                  const float* __restrict__ wgo,
                                                  const float* __restrict__ bgo,
                                                  float* __restrict__ out) {
    int n = blockIdx.x * 256 + threadIdx.x;
    if (n >= NN) return;
    float a0 = aggr[(size_t)n * 4 + 0], a1 = aggr[(size_t)n * 4 + 1];
    float a2 = aggr[(size_t)n * 4 + 2], a3 = aggr[(size_t)n * 4 + 3];
    float* reg = out + (size_t)NN * NCLS;
    float* obj = reg + (size_t)NN * 4;
#pragma unroll
    for (int k = 0; k < 4; ++k) {
        float acc = bgr[k];
        acc = fmaf(a0, wgr[k * 4 + 0], acc);
        acc = fmaf(a1, wgr[k * 4 + 1], acc);
        acc = fmaf(a2, wgr[k * 4 + 2], acc);
        acc = fmaf(a3, wgr[k * 4 + 3], acc);
        reg[(size_t)n * 4 + k] = acc;
    }
    obj[n] = fmaf(aggo[n], wgo[0], bgo[0]);
}

// ============================================================================
extern "C" void kernel_launch(void* const* d_in, const int* in_sizes, int n_in,
                              void* d_out, int out_size, void* d_ws, size_t ws_size,
                              hipStream_t stream) {
    const float* x   = (const float*)d_in[0];
    const float* pos = (const float*)d_in[1];
    const int* ei    = (const int*)d_in[2];
    const int* src = ei;
    const int* dst = ei + NE;
    const float* wl_stem = (const float*)d_in[3];
    const float* bl_stem = (const float*)d_in[4];
    const float* wg_stem = (const float*)d_in[5];
    const float* bg_stem = (const float*)d_in[6];
    const float* g_stem  = (const float*)d_in[7];
    const float* b_stem  = (const float*)d_in[8];
    const float* wl_c1 = (const float*)d_in[9];
    const float* bl_c1 = (const float*)d_in[10];
    const float* wg_c1 = (const float*)d_in[11];
    const float* bg_c1 = (const float*)d_in[12];
    const float* g_c1  = (const float*)d_in[13];
    const float* b_c1  = (const float*)d_in[14];
    const float* wl_c2 = (const float*)d_in[15];
    const float* bl_c2 = (const float*)d_in[16];
    const float* wg_c2 = (const float*)d_in[17];
    const float* bg_c2 = (const float*)d_in[18];
    const float* g_c2  = (const float*)d_in[19];
    const float* b_c2  = (const float*)d_in[20];
    const float* wl_reg = (const float*)d_in[21];
    const float* bl_reg = (const float*)d_in[22];
    const float* wg_reg = (const float*)d_in[23];
    const float* bg_reg = (const float*)d_in[24];
    const float* wl_cls = (const float*)d_in[25];
    const float* bl_cls = (const float*)d_in[26];
    const float* wg_cls = (const float*)d_in[27];
    const float* bg_cls = (const float*)d_in[28];
    const float* wl_obj = (const float*)d_in[29];
    const float* bl_obj = (const float*)d_in[30];
    const float* wg_obj = (const float*)d_in[31];
    const float* bg_obj = (const float*)d_in[32];

    float* ws = (float*)d_ws;
    // Arena: S0[N*128] | S1[N*64] | S2[N*64] | S3[N*64] | ints/smalls
    float* S0 = ws;
    float* S1 = S0 + (size_t)NN * 128;
    float* S2 = S1 + (size_t)NN * 64;
    float* S3 = S2 + (size_t)NN * 64;
    float* y12   = S0;
    float* y_cls = S0;
    float* aggc  = S1;     // N*104 spans S1+S2 (both dead by then)
    int*   rs   = (int*)(S3 + (size_t)NN * 64);   // NN+1 (padded)
    int*   cnt  = rs + 100016;
    int*   csrc = cnt + 100016;                   // NE
    float* pos2 = (float*)(csrc + NE);            // NN float2
    float* y_ro = pos2 + (size_t)NN * 2;          // NN*8
    float* aggr = y_ro + (size_t)NN * 8;          // NN*4
    float* aggo = aggr + (size_t)NN * 4;          // NN
    float* st   = aggo + NN;                      // 3*256
    float* st0 = st, *st1 = st + 256, *st2 = st + 512;
    float* wro = st + 768;                        // 5*66
    float* bro = wro + 336;
    int*   blk = (int*)(bro + 16);                // scan block sums

    hipMemsetAsync(cnt, 0, 100016 * sizeof(int), stream);
    hipMemsetAsync(st, 0, 768 * sizeof(float), stream);

    const int EB = (NE + 255) / 256;      // 6250
    const int NB = (NN + 255) / 256;      // 391
    const int N4 = (NN + 3) / 4;          // 25000
    const int NT = (NN + 63) / 64;        // 1563
    const int XB = NN * 16 / 256;         // 6250

    // ---- CSR build + pos2 ----
    pos2_k<<<NB, 256, 0, stream>>>(pos, (float2*)pos2);
    hist_k<<<EB, 256, 0, stream>>>(dst, cnt);
    scan1_k<<<NB_SCAN, 256, 0, stream>>>(cnt, rs, blk);
    scan2_k<<<1, 512, 0, stream>>>(blk);
    scan3_k<<<NB + 1, 256, 0, stream>>>(rs, blk, cnt);
    scatter_k<<<EB, 256, 0, stream>>>(src, dst, cnt, csrc);

    // ---- stem ----
    lin_k<64, 16, 64, 64, 66, 64, 1><<<NT, 256, 0, stream>>>(x, wl_stem, bl_stem, S1);
    edge1_k<<<N4, 256, 0, stream>>>(S1, (float2*)pos2, rs, csrc, wl_stem, S2);
    lin_k<64, 16, 64, 64, 64, 64, 1><<<NT, 256, 0, stream>>>(S2, wg_stem, bg_stem, S2);
    stats_k<<<128, 256, 0, stream>>>(S2, st0);
    bnpar_k<<<1, 64, 0, stream>>>(st0, g_stem, b_stem);
    bnrelu_k<<<XB, 256, 0, stream>>>(S2, st0);

    // ---- c1 + c2 (fused projection, shared edge pass) ----
    lin2_k<<<NT, 256, 0, stream>>>(S2, wl_c1, bl_c1, wl_c2, bl_c2, (float2*)y12);
    edge2_k<<<N4, 256, 0, stream>>>((const float2*)y12, (float2*)pos2, rs, csrc,
                                    wl_c1, wl_c2, S1, S3);
    lin_k<64, 16, 64, 64, 64, 64, 1><<<NT, 256, 0, stream>>>(S1, wg_c1, bg_c1, S1);
    stats_k<<<128, 256, 0, stream>>>(S1, st1);
    bnpar_k<<<1, 64, 0, stream>>>(st1, g_c1, b_c1);
    bnrelu_k<<<XB, 256, 0, stream>>>(S1, st1);
    lin_k<64, 16, 64, 64, 64, 64, 1><<<NT, 256, 0, stream>>>(S3, wg_c2, bg_c2, S3);
    stats_k<<<128, 256, 0, stream>>>(S3, st2);
    bnpar_k<<<1, 64, 0, stream>>>(st2, g_c2, b_c2);
    bnrelu_k<<<XB, 256, 0, stream>>>(S3, st2);

    // ---- reg + obj heads (input x1 = S1) ----
    pack_ro_k<<<1, 512, 0, stream>>>(wl_reg, bl_reg, wl_obj, bl_obj, wro, bro);
    lin_k<5, 2, 64, 64, 66, 8, 1><<<NT, 256, 0, stream>>>(S1, wro, bro, y_ro);
    edge_ro_k<<<N4, 256, 0, stream>>>(y_ro, (float2*)pos2, rs, csrc, wro, aggr, aggo);

    // ---- cls head (input x2 = S3) ----
    lin_k<101, 26, 64, 64, 66, 104, 1><<<NT, 256, 0, stream>>>(S3, wl_cls, bl_cls, y_cls);
    edge_cls_k<<<N4, 256, 0, stream>>>(y_cls, (float2*)pos2, rs, csrc, wl_cls, aggc);
    lin_k<101, 26, 101, 104, 101, 101, 1><<<NT, 256, 0, stream>>>(aggc, wg_cls, bg_cls,
                                                                  (float*)d_out);
    final_ro_k<<<NB, 256, 0, stream>>>(aggr, aggo, wg_reg, bg_reg, wg_obj, bg_obj,
                                       (float*)d_out);
}

// Round 5
// 1303.345 us; speedup vs baseline: 16.5435x; 1.1061x over previous
//
#include <hip/hip_runtime.h>

#define NN 100000
#define NE 1600000
#define NCLS 101
#define EPS_BN 1e-5f
#define NB_SCAN 391   // ceil(NN/256)
#define NINF (-__builtin_inff())

__device__ __forceinline__ int rl_i(int v, int j) {
    return __builtin_amdgcn_readlane(v, j);
}
__device__ __forceinline__ float rl_f(float v, int j) {
    return __int_as_float(__builtin_amdgcn_readlane(__float_as_int(v), j));
}

// ============================================================================
// CSR build: histogram -> block scan -> global scan -> scatter
// ============================================================================
__global__ __launch_bounds__(256) void hist_k(const int* __restrict__ dst,
                                              int* __restrict__ cnt) {
    int e = blockIdx.x * 256 + threadIdx.x;
    if (e < NE) atomicAdd(&cnt[dst[e]], 1);
}

__global__ __launch_bounds__(256) void scan1_k(const int* __restrict__ cnt,
                                               int* __restrict__ rs,
                                               int* __restrict__ blk) {
    __shared__ int sh[256];
    int t = threadIdx.x;
    int i = blockIdx.x * 256 + t;
    int v = (i < NN) ? cnt[i] : 0;
    sh[t] = v;
    __syncthreads();
    for (int off = 1; off < 256; off <<= 1) {
        int u = (t >= off) ? sh[t - off] : 0;
        __syncthreads();
        sh[t] += u;
        __syncthreads();
    }
    if (i < NN) rs[i] = sh[t] - v;
    if (t == 255) blk[blockIdx.x] = sh[255];
}

__global__ __launch_bounds__(512) void scan2_k(int* __restrict__ blk) {
    __shared__ int sh[512];
    int t = threadIdx.x;
    int v = (t < NB_SCAN) ? blk[t] : 0;
    sh[t] = v;
    __syncthreads();
    for (int off = 1; off < 512; off <<= 1) {
        int u = (t >= off) ? sh[t - off] : 0;
        __syncthreads();
        sh[t] += u;
        __syncthreads();
    }
    if (t < NB_SCAN) blk[t] = sh[t] - v;
}

__global__ __launch_bounds__(256) void scan3_k(int* __restrict__ rs,
                                               const int* __restrict__ blk,
                                               int* __restrict__ cur) {
    int i = blockIdx.x * 256 + threadIdx.x;
    if (i < NN) {
        int v = rs[i] + blk[i >> 8];
        rs[i] = v;
        cur[i] = v;
    } else if (i == NN) {
        rs[NN] = NE;
    }
}

__global__ __launch_bounds__(256) void scatter_k(const int* __restrict__ src,
                                                 const int* __restrict__ dst,
                                                 int* __restrict__ cur,
                                                 int* __restrict__ csrc) {
    int e = blockIdx.x * 256 + threadIdx.x;
    if (e >= NE) return;
    int d = dst[e];
    int p = atomicAdd(&cur[d], 1);
    csrc[p] = src[e];
}

__global__ __launch_bounds__(256) void pos2_k(const float* __restrict__ pos,
                                              float2* __restrict__ pos2) {
    int n = blockIdx.x * 256 + threadIdx.x;
    if (n < NN) pos2[n] = make_float2(pos[n * 3], pos[n * 3 + 1]);
}

// ============================================================================
// Node-side GEMM: out[n][c] = sum_j in[n][j]*w[c][j] + b[c]
// x-tile transposed in LDS [j][n] (stride MT+1); weight tile transposed in
// LDS [j][c] (channel-padded to CP=4*CPW) read via wave-uniform ds_read_b128
// broadcasts. Inner loop touches ONLY LDS (no s_load/vmem -> no lgkm mixing).
// MT=128 -> 2 nodes/thread; MT=64 -> 1. Wave wid owns channels [wid*CPW, ..).
// ============================================================================
template <int COUT, int CPW, int K, int IS, int WS, int OS, int MT>
__global__ __launch_bounds__(256) void gemm_k(const float* __restrict__ in,
                                              const float* __restrict__ w,
                                              const float* __restrict__ bias,
                                              float* __restrict__ out) {
    constexpr int CP = 4 * CPW;     // padded channels (CPW must be mult of 4)
    constexpr int RM = MT / 64;
    constexpr int XR = MT + 1;      // odd stride -> conflict-free staging writes
    __shared__ float xs[K * XR];
    __shared__ float wsh[K * CP];
    int base = blockIdx.x * MT;
    for (int p = threadIdx.x; p < K * CP; p += 256) {
        int j = p / CP, c = p - j * CP;
        wsh[p] = (c < COUT) ? w[c * WS + j] : 0.f;
    }
    for (int p = threadIdx.x; p < MT * K; p += 256) {
        int n = p / K, j = p - n * K;
        xs[j * XR + n] = (base + n < NN) ? in[(size_t)(base + n) * IS + j] : 0.f;
    }
    __syncthreads();
    int wid = __builtin_amdgcn_readfirstlane(threadIdx.x >> 6);
    int lane = threadIdx.x & 63;
    int c0 = wid * CPW;
    if (c0 >= COUT) return;     // no further barriers -> safe
    float acc[RM][CPW];
#pragma unroll
    for (int k = 0; k < CPW; ++k) {
        float bv = (c0 + k < COUT) ? bias[c0 + k] : 0.f;
#pragma unroll
        for (int r = 0; r < RM; ++r) acc[r][k] = bv;
    }
    for (int j = 0; j < K; ++j) {
        float a[RM];
#pragma unroll
        for (int r = 0; r < RM; ++r) a[r] = xs[j * XR + 64 * r + lane];
#pragma unroll
        for (int q = 0; q < CPW / 4; ++q) {
            float4 wv = *(const float4*)&wsh[j * CP + c0 + 4 * q];
#pragma unroll
            for (int r = 0; r < RM; ++r) {
                acc[r][4 * q + 0] = fmaf(a[r], wv.x, acc[r][4 * q + 0]);
                acc[r][4 * q + 1] = fmaf(a[r], wv.y, acc[r][4 * q + 1]);
                acc[r][4 * q + 2] = fmaf(a[r], wv.z, acc[r][4 * q + 2]);
                acc[r][4 * q + 3] = fmaf(a[r], wv.w, acc[r][4 * q + 3]);
            }
        }
    }
#pragma unroll
    for (int r = 0; r < RM; ++r) {
        int node = base + 64 * r + lane;
        if (node < NN) {
#pragma unroll
            for (int k = 0; k < CPW; ++k)
                if (c0 + k < COUT) out[(size_t)node * OS + c0 + k] = acc[r][k];
        }
    }
}

// interleave c1/c2 projection weights: wAB[2k][j]=wl1[k][j], wAB[2k+1][j]=wl2[k][j]
__global__ __launch_bounds__(256) void pack12_k(const float* __restrict__ wl1,
                                                const float* __restrict__ bl1,
                                                const float* __restrict__ wl2,
                                                const float* __restrict__ bl2,
                                                float* __restrict__ wAB,
                                                float* __restrict__ bAB) {
    int t = blockIdx.x * 256 + threadIdx.x;
    if (t < 128 * 64) {
        int r = t >> 6, j = t & 63;
        const float* srcw = (r & 1) ? wl2 : wl1;
        wAB[t] = srcw[(r >> 1) * 66 + j];
    }
    if (t < 128) bAB[t] = (t & 1) ? bl2[t >> 1] : bl1[t >> 1];
}

// ============================================================================
// Edge segment-max over CSR. Wave per node, lane = channel. 64-edge batches:
// indices+pos2 loaded coalesced once, broadcast via readlane; 8 gathers in
// flight per unrolled chunk (MLP).
// ============================================================================
__global__ __launch_bounds__(256) void edge1_k(const float* __restrict__ y,   // stride 64
                                               const float2* __restrict__ pos2,
                                               const int* __restrict__ rs,
                                               const int* __restrict__ csrc,
                                               const float* __restrict__ wl,  // (64,66)
                                               float* __restrict__ agg) {
    int wid = __builtin_amdgcn_readfirstlane(threadIdx.x >> 6);
    int lane = threadIdx.x & 63;
    int node = blockIdx.x * 4 + wid;
    if (node >= NN) return;
    float wp0 = wl[lane * 66 + 64], wp1 = wl[lane * 66 + 65];
    float2 pd = pos2[node];
    int i0 = rs[node], i1 = rs[node + 1];
    float acc = NINF;
    for (int ib = i0; ib < i1; ib += 64) {
        int m = i1 - ib;
        if (m > 64) m = 64;
        int t = ib + lane;
        int idx = (t < i1) ? csrc[t] : 0;
        float2 pp = pos2[idx];
        float ppx = pp.x, ppy = pp.y;
        int j = 0;
        for (; j + 8 <= m; j += 8) {
            float v[8];
#pragma unroll
            for (int q = 0; q < 8; ++q)
                v[q] = y[(size_t)rl_i(idx, j + q) * 64 + lane];
#pragma unroll
            for (int q = 0; q < 8; ++q) {
                float dx = rl_f(ppx, j + q) - pd.x, dy = rl_f(ppy, j + q) - pd.y;
                acc = fmaxf(acc, fmaf(dy, wp1, fmaf(dx, wp0, v[q])));
            }
        }
        for (; j + 4 <= m; j += 4) {
            float v[4];
#pragma unroll
            for (int q = 0; q < 4; ++q)
                v[q] = y[(size_t)rl_i(idx, j + q) * 64 + lane];
#pragma unroll
            for (int q = 0; q < 4; ++q) {
                float dx = rl_f(ppx, j + q) - pd.x, dy = rl_f(ppy, j + q) - pd.y;
                acc = fmaxf(acc, fmaf(dy, wp1, fmaf(dx, wp0, v[q])));
            }
        }
        for (; j < m; ++j) {
            int s = rl_i(idx, j);
            float v = y[(size_t)s * 64 + lane];
            acc = fmaxf(acc, fmaf(rl_f(ppy, j) - pd.y, wp1,
                                  fmaf(rl_f(ppx, j) - pd.x, wp0, v)));
        }
    }
    agg[(size_t)node * 64 + lane] = fmaxf(acc, 0.0f);
}

// y12 layout: [n][64]{float2} = (c1 proj, c2 proj)
__global__ __launch_bounds__(256) void edge2_k(const float2* __restrict__ y12,
                                               const float2* __restrict__ pos2,
                                               const int* __restrict__ rs,
                                               const int* __restrict__ csrc,
                                               const float* __restrict__ wlA,
                                               const float* __restrict__ wlB,
                                               float* __restrict__ a1,
                                               float* __restrict__ a2) {
    int wid = __builtin_amdgcn_readfirstlane(threadIdx.x >> 6);
    int lane = threadIdx.x & 63;
    int node = blockIdx.x * 4 + wid;
    if (node >= NN) return;
    float wa0 = wlA[lane * 66 + 64], wa1 = wlA[lane * 66 + 65];
    float wb0 = wlB[lane * 66 + 64], wb1 = wlB[lane * 66 + 65];
    float2 pd = pos2[node];
    int i0 = rs[node], i1 = rs[node + 1];
    float accA = NINF, accB = NINF;
    for (int ib = i0; ib < i1; ib += 64) {
        int m = i1 - ib;
        if (m > 64) m = 64;
        int t = ib + lane;
        int idx = (t < i1) ? csrc[t] : 0;
        float2 pp = pos2[idx];
        float ppx = pp.x, ppy = pp.y;
        int j = 0;
        for (; j + 8 <= m; j += 8) {
            float2 v[8];
#pragma unroll
            for (int q = 0; q < 8; ++q)
                v[q] = y12[(size_t)rl_i(idx, j + q) * 64 + lane];
#pragma unroll
            for (int q = 0; q < 8; ++q) {
                float dx = rl_f(ppx, j + q) - pd.x, dy = rl_f(ppy, j + q) - pd.y;
                accA = fmaxf(accA, fmaf(dy, wa1, fmaf(dx, wa0, v[q].x)));
                accB = fmaxf(accB, fmaf(dy, wb1, fmaf(dx, wb0, v[q].y)));
            }
        }
        for (; j + 4 <= m; j += 4) {
            float2 v[4];
#pragma unroll
            for (int q = 0; q < 4; ++q)
                v[q] = y12[(size_t)rl_i(idx, j + q) * 64 + lane];
#pragma unroll
            for (int q = 0; q < 4; ++q) {
                float dx = rl_f(ppx, j + q) - pd.x, dy = rl_f(ppy, j + q) - pd.y;
                accA = fmaxf(accA, fmaf(dy, wa1, fmaf(dx, wa0, v[q].x)));
                accB = fmaxf(accB, fmaf(dy, wb1, fmaf(dx, wb0, v[q].y)));
            }
        }
        for (; j < m; ++j) {
            float2 v = y12[(size_t)rl_i(idx, j) * 64 + lane];
            float dx = rl_f(ppx, j) - pd.x, dy = rl_f(ppy, j) - pd.y;
            accA = fmaxf(accA, fmaf(dy, wa1, fmaf(dx, wa0, v.x)));
            accB = fmaxf(accB, fmaf(dy, wb1, fmaf(dx, wb0, v.y)));
        }
    }
    a1[(size_t)node * 64 + lane] = fmaxf(accA, 0.0f);
    a2[(size_t)node * 64 + lane] = fmaxf(accB, 0.0f);
}

// cls: wave per node, lane covers channels {lane, lane+64 (clamped)}
__global__ __launch_bounds__(256) void edge_cls_k(const float* __restrict__ y,  // stride 104
                                                  const float2* __restrict__ pos2,
                                                  const int* __restrict__ rs,
                                                  const int* __restrict__ csrc,
                                                  const float* __restrict__ wl,  // (101,66)
                                                  float* __restrict__ agg) {     // stride 104
    int wid = __builtin_amdgcn_readfirstlane(threadIdx.x >> 6);
    int lane = threadIdx.x & 63;
    int node = blockIdx.x * 4 + wid;
    if (node >= NN) return;
    int chi = (lane + 64 < NCLS) ? (lane + 64) : (NCLS - 1);
    float wa0 = wl[lane * 66 + 64], wa1 = wl[lane * 66 + 65];
    float wb0 = wl[chi * 66 + 64], wb1 = wl[chi * 66 + 65];
    float2 pd = pos2[node];
    int i0 = rs[node], i1 = rs[node + 1];
    float accA = NINF, accB = NINF;
    for (int ib = i0; ib < i1; ib += 64) {
        int m = i1 - ib;
        if (m > 64) m = 64;
        int t = ib + lane;
        int idx = (t < i1) ? csrc[t] : 0;
        float2 pp = pos2[idx];
        float ppx = pp.x, ppy = pp.y;
        int j = 0;
        for (; j + 4 <= m; j += 4) {
            float va[4], vb[4];
#pragma unroll
            for (int q = 0; q < 4; ++q) {
                size_t row = (size_t)rl_i(idx, j + q) * 104;
                va[q] = y[row + lane];
                vb[q] = y[row + chi];
            }
#pragma unroll
            for (int q = 0; q < 4; ++q) {
                float dx = rl_f(ppx, j + q) - pd.x, dy = rl_f(ppy, j + q) - pd.y;
                accA = fmaxf(accA, fmaf(dy, wa1, fmaf(dx, wa0, va[q])));
                accB = fmaxf(accB, fmaf(dy, wb1, fmaf(dx, wb0, vb[q])));
            }
        }
        for (; j < m; ++j) {
            size_t row = (size_t)rl_i(idx, j) * 104;
            float va = y[row + lane];
            float vb = y[row + chi];
            float dx = rl_f(ppx, j) - pd.x, dy = rl_f(ppy, j) - pd.y;
            accA = fmaxf(accA, fmaf(dy, wa1, fmaf(dx, wa0, va)));
            accB = fmaxf(accB, fmaf(dy, wb1, fmaf(dx, wb0, vb)));
        }
    }
    agg[(size_t)node * 104 + lane] = fmaxf(accA, 0.0f);
    if (lane + 64 < NCLS) agg[(size_t)node * 104 + 64 + lane] = fmaxf(accB, 0.0f);
}

// reg+obj: 5 channels packed stride 8; wave = 8 edge-slots x 8 channel-slots
__global__ __launch_bounds__(256) void edge_ro_k(const float* __restrict__ y,  // stride 8
                                                 const float2* __restrict__ pos2,
                                                 const int* __restrict__ rs,
                                                 const int* __restrict__ csrc,
                                                 const float* __restrict__ wro,  // (5,66)
                                                 float* __restrict__ aggr,
                                                 float* __restrict__ aggo) {
    int wid = __builtin_amdgcn_readfirstlane(threadIdx.x >> 6);
    int lane = threadIdx.x & 63;
    int node = blockIdx.x * 4 + wid;
    if (node >= NN) return;
    int k = lane >> 3, c = lane & 7;
    int cc = (c < 5) ? c : 4;
    float wp0 = wro[cc * 66 + 64], wp1 = wro[cc * 66 + 65];
    float2 pd = pos2[node];
    int i0 = rs[node], i1 = rs[node + 1];
    float acc = NINF;
    for (int i = i0 + k; i < i1; i += 8) {
        int s = csrc[i];
        float2 p = pos2[s];
        float v = y[(size_t)s * 8 + cc];
        acc = fmaxf(acc, fmaf(p.y - pd.y, wp1, fmaf(p.x - pd.x, wp0, v)));
    }
    acc = fmaxf(acc, __shfl_xor(acc, 8, 64));
    acc = fmaxf(acc, __shfl_xor(acc, 16, 64));
    acc = fmaxf(acc, __shfl_xor(acc, 32, 64));
    acc = fmaxf(acc, 0.0f);
    if (lane < 5) {
        if (lane < 4) aggr[(size_t)node * 4 + lane] = acc;
        else          aggo[node] = acc;
    }
}

// ============================================================================
// BN: column sums -> params -> apply
// ============================================================================
__global__ __launch_bounds__(256) void stats_k(const float* __restrict__ x,
                                               float* __restrict__ st) {
    __shared__ float sS[4][64], sQ[4][64];
    int wid = threadIdx.x >> 6, lane = threadIdx.x & 63;
    int stride = gridDim.x * 4;
    float s = 0.f, q = 0.f;
    for (int n = blockIdx.x * 4 + wid; n < NN; n += stride) {
        float v = x[(size_t)n * 64 + lane];
        s += v;
        q = fmaf(v, v, q);
    }
    sS[wid][lane] = s;
    sQ[wid][lane] = q;
    __syncthreads();
    if (wid == 0) {
        float ts = sS[0][lane] + sS[1][lane] + sS[2][lane] + sS[3][lane];
        float tq = sQ[0][lane] + sQ[1][lane] + sQ[2][lane] + sQ[3][lane];
        atomicAdd(&st[lane], ts);
        atomicAdd(&st[64 + lane], tq);
    }
}

__global__ void bnpar_k(float* __restrict__ st, const float* __restrict__ g,
                        const float* __restrict__ b) {
    int c = threadIdx.x;
    if (c >= 64) return;
    float mu = st[c] * (1.0f / NN);
    float var = st[64 + c] * (1.0f / NN) - mu * mu;
    float sc = g[c] * rsqrtf(var + EPS_BN);
    st[128 + c] = sc;
    st[192 + c] = b[c] - mu * sc;
}

__global__ __launch_bounds__(256) void bnrelu_k(float* __restrict__ x,
                                                const float* __restrict__ st) {
    int i = blockIdx.x * 256 + threadIdx.x;   // over NN*16 float4s
    if (i >= NN * 16) return;
    float4 v = ((float4*)x)[i];
    int c0 = (i * 4) & 63;
    v.x = fmaxf(fmaf(v.x, st[128 + c0 + 0], st[192 + c0 + 0]), 0.f);
    v.y = fmaxf(fmaf(v.y, st[128 + c0 + 1], st[192 + c0 + 1]), 0.f);
    v.z = fmaxf(fmaf(v.z, st[128 + c0 + 2], st[192 + c0 + 2]), 0.f);
    v.w = fmaxf(fmaf(v.w, st[128 + c0 + 3], st[192 + c0 + 3]), 0.f);
    ((float4*)x)[i] = v;
}

__global__ void pack_ro_k(const float* __restrict__ wlr, const float* __restrict__ blr,
                          const float* __restrict__ wlo, const float* __restrict__ blo,
                          float* __restrict__ wro, float* __restrict__ bro) {
    int t = threadIdx.x;
    if (t < 5 * 66) {
        int cc = t / 66, j = t - cc * 66;
        wro[t] = (cc < 4) ? wlr[t] : wlo[j];
    }
    if (t < 5) bro[t] = (t < 4) ? blr[t] : blo[0];
}

__global__ __launch_bounds__(256) void final_ro_k(const float* __restrict__ aggr,
                                                  const float* __restrict__ aggo,
                                                  const float* __restrict__ wgr,
                                                  const float* __restrict__ bgr,
                                                  const float* __restrict__ wgo,
                                                  const float* __restrict__ bgo,
                                                  float* __restrict__ out) {
    int n = blockIdx.x * 256 + threadIdx.x;
    if (n >= NN) return;
    float a0 = aggr[(size_t)n * 4 + 0], a1 = aggr[(size_t)n * 4 + 1];
    float a2 = aggr[(size_t)n * 4 + 2], a3 = aggr[(size_t)n * 4 + 3];
    float* reg = out + (size_t)NN * NCLS;
    float* obj = reg + (size_t)NN * 4;
#pragma unroll
    for (int k = 0; k < 4; ++k) {
        float acc = bgr[k];
        acc = fmaf(a0, wgr[k * 4 + 0], acc);
        acc = fmaf(a1, wgr[k * 4 + 1], acc);
        acc = fmaf(a2, wgr[k * 4 + 2], acc);
        acc = fmaf(a3, wgr[k * 4 + 3], acc);
        reg[(size_t)n * 4 + k] = acc;
    }
    obj[n] = fmaf(aggo[n], wgo[0], bgo[0]);
}

// ============================================================================
extern "C" void kernel_launch(void* const* d_in, const int* in_sizes, int n_in,
                              void* d_out, int out_size, void* d_ws, size_t ws_size,
                              hipStream_t stream) {
    const float* x   = (const float*)d_in[0];
    const float* pos = (const float*)d_in[1];
    const int* ei    = (const int*)d_in[2];
    const int* src = ei;
    const int* dst = ei + NE;
    const float* wl_stem = (const float*)d_in[3];
    const float* bl_stem = (const float*)d_in[4];
    const float* wg_stem = (const float*)d_in[5];
    const float* bg_stem = (const float*)d_in[6];
    const float* g_stem  = (const float*)d_in[7];
    const float* b_stem  = (const float*)d_in[8];
    const float* wl_c1 = (const float*)d_in[9];
    const float* bl_c1 = (const float*)d_in[10];
    const float* wg_c1 = (const float*)d_in[11];
    const float* bg_c1 = (const float*)d_in[12];
    const float* g_c1  = (const float*)d_in[13];
    const float* b_c1  = (const float*)d_in[14];
    const float* wl_c2 = (const float*)d_in[15];
    const float* bl_c2 = (const float*)d_in[16];
    const float* wg_c2 = (const float*)d_in[17];
    const float* bg_c2 = (const float*)d_in[18];
    const float* g_c2  = (const float*)d_in[19];
    const float* b_c2  = (const float*)d_in[20];
    const float* wl_reg = (const float*)d_in[21];
    const float* bl_reg = (const float*)d_in[22];
    const float* wg_reg = (const float*)d_in[23];
    const float* bg_reg = (const float*)d_in[24];
    const float* wl_cls = (const float*)d_in[25];
    const float* bl_cls = (const float*)d_in[26];
    const float* wg_cls = (const float*)d_in[27];
    const float* bg_cls = (const float*)d_in[28];
    const float* wl_obj = (const float*)d_in[29];
    const float* bl_obj = (const float*)d_in[30];
    const float* wg_obj = (const float*)d_in[31];
    const float* bg_obj = (const float*)d_in[32];

    float* ws = (float*)d_ws;
    // Arena: S0[N*128] | S1[N*64] | S2[N*64] | S3[N*64] | ints/smalls
    float* S0 = ws;
    float* S1 = S0 + (size_t)NN * 128;
    float* S2 = S1 + (size_t)NN * 64;
    float* S3 = S2 + (size_t)NN * 64;
    float* y12   = S0;
    float* y_cls = S0;
    float* aggc  = S1;     // N*104 spans S1+S2 (both dead by then)
    int*   rs   = (int*)(S3 + (size_t)NN * 64);   // NN+1 (padded)
    int*   cnt  = rs + 100016;
    int*   csrc = cnt + 100016;                   // NE
    float* pos2 = (float*)(csrc + NE);            // NN float2
    float* y_ro = pos2 + (size_t)NN * 2;          // NN*8
    float* aggr = y_ro + (size_t)NN * 8;          // NN*4
    float* aggo = aggr + (size_t)NN * 4;          // NN
    float* st   = aggo + NN;                      // 3*256
    float* st0 = st, *st1 = st + 256, *st2 = st + 512;
    float* wro = st + 768;                        // 5*66
    float* bro = wro + 336;
    int*   blk = (int*)(bro + 16);                // scan block sums (512)
    float* wAB = (float*)(blk + 512);             // 128*64 packed c1c2 weights
    float* bAB = wAB + 128 * 64;                  // 128

    hipMemsetAsync(cnt, 0, 100016 * sizeof(int), stream);
    hipMemsetAsync(st, 0, 768 * sizeof(float), stream);

    const int EB = (NE + 255) / 256;      // 6250
    const int NB = (NN + 255) / 256;      // 391
    const int N4 = (NN + 3) / 4;          // 25000
    const int G128 = (NN + 127) / 128;    // 782
    const int G64  = (NN + 63) / 64;      // 1563
    const int XB = NN * 16 / 256;         // 6250

    // ---- CSR build + pos2 + weight packing ----
    pos2_k<<<NB, 256, 0, stream>>>(pos, (float2*)pos2);
    hist_k<<<EB, 256, 0, stream>>>(dst, cnt);
    scan1_k<<<NB_SCAN, 256, 0, stream>>>(cnt, rs, blk);
    scan2_k<<<1, 512, 0, stream>>>(blk);
    scan3_k<<<NB + 1, 256, 0, stream>>>(rs, blk, cnt);
    scatter_k<<<EB, 256, 0, stream>>>(src, dst, cnt, csrc);
    pack_ro_k<<<1, 512, 0, stream>>>(wl_reg, bl_reg, wl_obj, bl_obj, wro, bro);
    pack12_k<<<32, 256, 0, stream>>>(wl_c1, bl_c1, wl_c2, bl_c2, wAB, bAB);

    // ---- stem ----
    gemm_k<64, 16, 64, 64, 66, 64, 128><<<G128, 256, 0, stream>>>(x, wl_stem, bl_stem, S1);
    edge1_k<<<N4, 256, 0, stream>>>(S1, (float2*)pos2, rs, csrc, wl_stem, S2);
    gemm_k<64, 16, 64, 64, 64, 64, 128><<<G128, 256, 0, stream>>>(S2, wg_stem, bg_stem, S2);
    stats_k<<<512, 256, 0, stream>>>(S2, st0);
    bnpar_k<<<1, 64, 0, stream>>>(st0, g_stem, b_stem);
    bnrelu_k<<<XB, 256, 0, stream>>>(S2, st0);

    // ---- c1 + c2 (packed projection, shared edge pass) ----
    gemm_k<128, 32, 64, 64, 64, 128, 128><<<G128, 256, 0, stream>>>(S2, wAB, bAB, y12);
    edge2_k<<<N4, 256, 0, stream>>>((const float2*)y12, (float2*)pos2, rs, csrc,
                                    wl_c1, wl_c2, S1, S3);
    gemm_k<64, 16, 64, 64, 64, 64, 128><<<G128, 256, 0, stream>>>(S1, wg_c1, bg_c1, S1);
    stats_k<<<512, 256, 0, stream>>>(S1, st1);
    bnpar_k<<<1, 64, 0, stream>>>(st1, g_c1, b_c1);
    bnrelu_k<<<XB, 256, 0, stream>>>(S1, st1);
    gemm_k<64, 16, 64, 64, 64, 64, 128><<<G128, 256, 0, stream>>>(S3, wg_c2, bg_c2, S3);
    stats_k<<<512, 256, 0, stream>>>(S3, st2);
    bnpar_k<<<1, 64, 0, stream>>>(st2, g_c2, b_c2);
    bnrelu_k<<<XB, 256, 0, stream>>>(S3, st2);

    // ---- reg + obj heads (input x1 = S1) ----
    gemm_k<5, 4, 64, 64, 66, 8, 128><<<G128, 256, 0, stream>>>(S1, wro, bro, y_ro);
    edge_ro_k<<<N4, 256, 0, stream>>>(y_ro, (float2*)pos2, rs, csrc, wro, aggr, aggo);

    // ---- cls head (input x2 = S3) ----
    gemm_k<101, 28, 64, 64, 66, 104, 128><<<G128, 256, 0, stream>>>(S3, wl_cls, bl_cls, y_cls);
    edge_cls_k<<<N4, 256, 0, stream>>>(y_cls, (float2*)pos2, rs, csrc, wl_cls, aggc);
    gemm_k<101, 28, 101, 104, 101, 101, 64><<<G64, 256, 0, stream>>>(aggc, wg_cls, bg_cls,
                                                                     (float*)d_out);
    final_ro_k<<<NB, 256, 0, stream>>>(aggr, aggo, wg_reg, bg_reg, wg_obj, bg_obj,
                                       (float*)d_out);
}

// Round 6
// 1191.799 us; speedup vs baseline: 18.0919x; 1.0936x over previous
//
#include <hip/hip_runtime.h>

#define NN 100000
#define NE 1600000
#define NCLS 101
#define EPS_BN 1e-5f
#define NB_SCAN 391   // ceil(NN/256)
#define NINF (-__builtin_inff())

__device__ __forceinline__ int rl_i(int v, int j) {
    return __builtin_amdgcn_readlane(v, j);
}
__device__ __forceinline__ float rl_f(float v, int j) {
    return __int_as_float(__builtin_amdgcn_readlane(__float_as_int(v), j));
}

// ============================================================================
// CSR build: histogram -> block scan -> global scan -> scatter
// ============================================================================
__global__ __launch_bounds__(256) void hist_k(const int* __restrict__ dst,
                                              int* __restrict__ cnt) {
    int e = blockIdx.x * 256 + threadIdx.x;
    if (e < NE) atomicAdd(&cnt[dst[e]], 1);
}

__global__ __launch_bounds__(256) void scan1_k(const int* __restrict__ cnt,
                                               int* __restrict__ rs,
                                               int* __restrict__ blk) {
    __shared__ int sh[256];
    int t = threadIdx.x;
    int i = blockIdx.x * 256 + t;
    int v = (i < NN) ? cnt[i] : 0;
    sh[t] = v;
    __syncthreads();
    for (int off = 1; off < 256; off <<= 1) {
        int u = (t >= off) ? sh[t - off] : 0;
        __syncthreads();
        sh[t] += u;
        __syncthreads();
    }
    if (i < NN) rs[i] = sh[t] - v;
    if (t == 255) blk[blockIdx.x] = sh[255];
}

__global__ __launch_bounds__(512) void scan2_k(int* __restrict__ blk) {
    __shared__ int sh[512];
    int t = threadIdx.x;
    int v = (t < NB_SCAN) ? blk[t] : 0;
    sh[t] = v;
    __syncthreads();
    for (int off = 1; off < 512; off <<= 1) {
        int u = (t >= off) ? sh[t - off] : 0;
        __syncthreads();
        sh[t] += u;
        __syncthreads();
    }
    if (t < NB_SCAN) blk[t] = sh[t] - v;
}

__global__ __launch_bounds__(256) void scan3_k(int* __restrict__ rs,
                                               const int* __restrict__ blk,
                                               int* __restrict__ cur) {
    int i = blockIdx.x * 256 + threadIdx.x;
    if (i < NN) {
        int v = rs[i] + blk[i >> 8];
        rs[i] = v;
        cur[i] = v;
    } else if (i == NN) {
        rs[NN] = NE;
    }
}

__global__ __launch_bounds__(256) void scatter_k(const int* __restrict__ src,
                                                 const int* __restrict__ dst,
                                                 int* __restrict__ cur,
                                                 int* __restrict__ csrc) {
    int e = blockIdx.x * 256 + threadIdx.x;
    if (e >= NE) return;
    int d = dst[e];
    int p = atomicAdd(&cur[d], 1);
    csrc[p] = src[e];
}

__global__ __launch_bounds__(256) void pos2_k(const float* __restrict__ pos,
                                              float2* __restrict__ pos2) {
    int n = blockIdx.x * 256 + threadIdx.x;
    if (n < NN) pos2[n] = make_float2(pos[n * 3], pos[n * 3 + 1]);
}

// ============================================================================
// One-shot weight packing: transpose every GEMM weight into padded [K][CP]
// layout so gemm_k's staging is a straight coalesced float4 copy.
// ============================================================================
__global__ __launch_bounds__(256) void pack_all_k(
    const float* __restrict__ wl_stem, const float* __restrict__ wg_stem,
    const float* __restrict__ wl_c1, const float* __restrict__ bl_c1,
    const float* __restrict__ wl_c2, const float* __restrict__ bl_c2,
    const float* __restrict__ wg_c1, const float* __restrict__ wg_c2,
    const float* __restrict__ wl_reg, const float* __restrict__ wl_obj,
    const float* __restrict__ bl_reg, const float* __restrict__ bl_obj,
    const float* __restrict__ wl_cls, const float* __restrict__ wg_cls,
    float* __restrict__ wT_sp, float* __restrict__ wT_sg,
    float* __restrict__ wT_12, float* __restrict__ wT_g1,
    float* __restrict__ wT_g2, float* __restrict__ wT_ro,
    float* __restrict__ wT_cp, float* __restrict__ wT_cg,
    float* __restrict__ bAB, float* __restrict__ wro, float* __restrict__ bro) {
    int u = blockIdx.x * 256 + threadIdx.x;
    if (u < 4096) { int j = u >> 6, c = u & 63; wT_sp[u] = wl_stem[c * 66 + j]; return; }
    u -= 4096;
    if (u < 4096) { int j = u >> 6, c = u & 63; wT_sg[u] = wg_stem[c * 64 + j]; return; }
    u -= 4096;
    if (u < 8192) { int j = u >> 7, c = u & 127; int k = c >> 1;
        wT_12[u] = ((c & 1) ? wl_c2 : wl_c1)[k * 66 + j]; return; }
    u -= 8192;
    if (u < 4096) { int j = u >> 6, c = u & 63; wT_g1[u] = wg_c1[c * 64 + j]; return; }
    u -= 4096;
    if (u < 4096) { int j = u >> 6, c = u & 63; wT_g2[u] = wg_c2[c * 64 + j]; return; }
    u -= 4096;
    if (u < 1024) { int j = u >> 4, c = u & 15;
        wT_ro[u] = (c < 4) ? wl_reg[c * 66 + j] : ((c == 4) ? wl_obj[j] : 0.f); return; }
    u -= 1024;
    if (u < 7168) { int j = u / 112, c = u - j * 112;
        wT_cp[u] = (c < NCLS) ? wl_cls[c * 66 + j] : 0.f; return; }
    u -= 7168;
    if (u < 11312) { int j = u / 112, c = u - j * 112;
        wT_cg[u] = (c < NCLS) ? wg_cls[c * NCLS + j] : 0.f; return; }
    u -= 11312;
    if (u < 128) { bAB[u] = (u & 1) ? bl_c2[u >> 1] : bl_c1[u >> 1]; return; }
    u -= 128;
    if (u < 330) { int cc = u / 66, j = u - cc * 66;
        wro[u] = (cc < 4) ? wl_reg[u] : wl_obj[j]; return; }
    u -= 330;
    if (u < 5) bro[u] = (u < 4) ? bl_reg[u] : bl_obj[0];
}

// ============================================================================
// Node-side GEMM: out[n][c] = sum_j xs(n,j)*wT[j][c] + b[c]
// wT pre-transposed [K][CP] -> staging is coalesced float4 copy + linear LDS
// writes. x-tile transposed in LDS [j][n] (odd stride). Optional fused
// BN+ReLU on input staging (BNF): v = relu(v*st[128+j] + st[192+j]).
// Inner loop: LDS only. Wave wid owns channels [wid*CPW, wid*CPW+CPW).
// ============================================================================
template <int COUT, int CPW, int K, int IS, int OS, int MT, bool BNF>
__global__ __launch_bounds__(256) void gemm_k(const float* __restrict__ in,
                                              const float* __restrict__ wT,
                                              const float* __restrict__ bias,
                                              const float* __restrict__ st,
                                              float* __restrict__ out) {
    constexpr int CP = 4 * CPW;
    constexpr int RM = MT / 64;
    constexpr int XR = MT + 1;
    __shared__ __align__(16) float xs[K * XR];
    __shared__ __align__(16) float wsh[K * CP];
    int base = blockIdx.x * MT;
    for (int p = threadIdx.x; p < K * CP / 4; p += 256)
        ((float4*)wsh)[p] = ((const float4*)wT)[p];
    for (int p = threadIdx.x; p < MT * K; p += 256) {
        int n = p / K, j = p - n * K;
        float v = (base + n < NN) ? in[(size_t)(base + n) * IS + j] : 0.f;
        if constexpr (BNF) v = fmaxf(fmaf(v, st[128 + j], st[192 + j]), 0.f);
        xs[j * XR + n] = v;
    }
    __syncthreads();
    int wid = __builtin_amdgcn_readfirstlane(threadIdx.x >> 6);
    int lane = threadIdx.x & 63;
    int c0 = wid * CPW;
    if (c0 >= COUT) return;     // after the only barrier -> safe
    float acc[RM][CPW];
#pragma unroll
    for (int k = 0; k < CPW; ++k) {
        float bv = (c0 + k < COUT) ? bias[c0 + k] : 0.f;
#pragma unroll
        for (int r = 0; r < RM; ++r) acc[r][k] = bv;
    }
    for (int j = 0; j < K; ++j) {
        float a[RM];
#pragma unroll
        for (int r = 0; r < RM; ++r) a[r] = xs[j * XR + 64 * r + lane];
#pragma unroll
        for (int q = 0; q < CPW / 4; ++q) {
            float4 wv = *(const float4*)&wsh[j * CP + c0 + 4 * q];
#pragma unroll
            for (int r = 0; r < RM; ++r) {
                acc[r][4 * q + 0] = fmaf(a[r], wv.x, acc[r][4 * q + 0]);
                acc[r][4 * q + 1] = fmaf(a[r], wv.y, acc[r][4 * q + 1]);
                acc[r][4 * q + 2] = fmaf(a[r], wv.z, acc[r][4 * q + 2]);
                acc[r][4 * q + 3] = fmaf(a[r], wv.w, acc[r][4 * q + 3]);
            }
        }
    }
#pragma unroll
    for (int r = 0; r < RM; ++r) {
        int node = base + 64 * r + lane;
        if (node < NN) {
#pragma unroll
            for (int k = 0; k < CPW; ++k)
                if (c0 + k < COUT) out[(size_t)node * OS + c0 + k] = acc[r][k];
        }
    }
}

// ============================================================================
// Edge segment-max over CSR. Wave per node, lane = channel. 64-edge batches:
// indices+pos2 loaded coalesced once, broadcast via readlane; 8 gathers in
// flight per unrolled chunk (MLP).
// ============================================================================
__global__ __launch_bounds__(256) void edge1_k(const float* __restrict__ y,   // stride 64
                                               const float2* __restrict__ pos2,
                                               const int* __restrict__ rs,
                                               const int* __restrict__ csrc,
                                               const float* __restrict__ wl,  // (64,66)
                                               float* __restrict__ agg) {
    int wid = __builtin_amdgcn_readfirstlane(threadIdx.x >> 6);
    int lane = threadIdx.x & 63;
    int node = blockIdx.x * 4 + wid;
    if (node >= NN) return;
    float wp0 = wl[lane * 66 + 64], wp1 = wl[lane * 66 + 65];
    float2 pd = pos2[node];
    int i0 = rs[node], i1 = rs[node + 1];
    float acc = NINF;
    for (int ib = i0; ib < i1; ib += 64) {
        int m = i1 - ib;
        if (m > 64) m = 64;
        int t = ib + lane;
        int idx = (t < i1) ? csrc[t] : 0;
        float2 pp = pos2[idx];
        float ppx = pp.x, ppy = pp.y;
        int j = 0;
        for (; j + 8 <= m; j += 8) {
            float v[8];
#pragma unroll
            for (int q = 0; q < 8; ++q)
                v[q] = y[(size_t)rl_i(idx, j + q) * 64 + lane];
#pragma unroll
            for (int q = 0; q < 8; ++q) {
                float dx = rl_f(ppx, j + q) - pd.x, dy = rl_f(ppy, j + q) - pd.y;
                acc = fmaxf(acc, fmaf(dy, wp1, fmaf(dx, wp0, v[q])));
            }
        }
        for (; j + 4 <= m; j += 4) {
            float v[4];
#pragma unroll
            for (int q = 0; q < 4; ++q)
                v[q] = y[(size_t)rl_i(idx, j + q) * 64 + lane];
#pragma unroll
            for (int q = 0; q < 4; ++q) {
                float dx = rl_f(ppx, j + q) - pd.x, dy = rl_f(ppy, j + q) - pd.y;
                acc = fmaxf(acc, fmaf(dy, wp1, fmaf(dx, wp0, v[q])));
            }
        }
        for (; j < m; ++j) {
            int s = rl_i(idx, j);
            float v = y[(size_t)s * 64 + lane];
            acc = fmaxf(acc, fmaf(rl_f(ppy, j) - pd.y, wp1,
                                  fmaf(rl_f(ppx, j) - pd.x, wp0, v)));
        }
    }
    agg[(size_t)node * 64 + lane] = fmaxf(acc, 0.0f);
}

// y12 layout: [n][64]{float2} = (c1 proj, c2 proj)
__global__ __launch_bounds__(256) void edge2_k(const float2* __restrict__ y12,
                                               const float2* __restrict__ pos2,
                                               const int* __restrict__ rs,
                                               const int* __restrict__ csrc,
                                               const float* __restrict__ wlA,
                                               const float* __restrict__ wlB,
                                               float* __restrict__ a1,
                                               float* __restrict__ a2) {
    int wid = __builtin_amdgcn_readfirstlane(threadIdx.x >> 6);
    int lane = threadIdx.x & 63;
    int node = blockIdx.x * 4 + wid;
    if (node >= NN) return;
    float wa0 = wlA[lane * 66 + 64], wa1 = wlA[lane * 66 + 65];
    float wb0 = wlB[lane * 66 + 64], wb1 = wlB[lane * 66 + 65];
    float2 pd = pos2[node];
    int i0 = rs[node], i1 = rs[node + 1];
    float accA = NINF, accB = NINF;
    for (int ib = i0; ib < i1; ib += 64) {
        int m = i1 - ib;
        if (m > 64) m = 64;
        int t = ib + lane;
        int idx = (t < i1) ? csrc[t] : 0;
        float2 pp = pos2[idx];
        float ppx = pp.x, ppy = pp.y;
        int j = 0;
        for (; j + 8 <= m; j += 8) {
            float2 v[8];
#pragma unroll
            for (int q = 0; q < 8; ++q)
                v[q] = y12[(size_t)rl_i(idx, j + q) * 64 + lane];
#pragma unroll
            for (int q = 0; q < 8; ++q) {
                float dx = rl_f(ppx, j + q) - pd.x, dy = rl_f(ppy, j + q) - pd.y;
                accA = fmaxf(accA, fmaf(dy, wa1, fmaf(dx, wa0, v[q].x)));
                accB = fmaxf(accB, fmaf(dy, wb1, fmaf(dx, wb0, v[q].y)));
            }
        }
        for (; j + 4 <= m; j += 4) {
            float2 v[4];
#pragma unroll
            for (int q = 0; q < 4; ++q)
                v[q] = y12[(size_t)rl_i(idx, j + q) * 64 + lane];
#pragma unroll
            for (int q = 0; q < 4; ++q) {
                float dx = rl_f(ppx, j + q) - pd.x, dy = rl_f(ppy, j + q) - pd.y;
                accA = fmaxf(accA, fmaf(dy, wa1, fmaf(dx, wa0, v[q].x)));
                accB = fmaxf(accB, fmaf(dy, wb1, fmaf(dx, wb0, v[q].y)));
            }
        }
        for (; j < m; ++j) {
            float2 v = y12[(size_t)rl_i(idx, j) * 64 + lane];
            float dx = rl_f(ppx, j) - pd.x, dy = rl_f(ppy, j) - pd.y;
            accA = fmaxf(accA, fmaf(dy, wa1, fmaf(dx, wa0, v.x)));
            accB = fmaxf(accB, fmaf(dy, wb1, fmaf(dx, wb0, v.y)));
        }
    }
    a1[(size_t)node * 64 + lane] = fmaxf(accA, 0.0f);
    a2[(size_t)node * 64 + lane] = fmaxf(accB, 0.0f);
}

// cls: wave per node, lane covers channels {lane, lane+64 (clamped)}
__global__ __launch_bounds__(256) void edge_cls_k(const float* __restrict__ y,  // stride 104
                                                  const float2* __restrict__ pos2,
                                                  const int* __restrict__ rs,
                                                  const int* __restrict__ csrc,
                                                  const float* __restrict__ wl,  // (101,66)
                                                  float* __restrict__ agg) {     // stride 104
    int wid = __builtin_amdgcn_readfirstlane(threadIdx.x >> 6);
    int lane = threadIdx.x & 63;
    int node = blockIdx.x * 4 + wid;
    if (node >= NN) return;
    int chi = (lane + 64 < NCLS) ? (lane + 64) : (NCLS - 1);
    float wa0 = wl[lane * 66 + 64], wa1 = wl[lane * 66 + 65];
    float wb0 = wl[chi * 66 + 64], wb1 = wl[chi * 66 + 65];
    float2 pd = pos2[node];
    int i0 = rs[node], i1 = rs[node + 1];
    float accA = NINF, accB = NINF;
    for (int ib = i0; ib < i1; ib += 64) {
        int m = i1 - ib;
        if (m > 64) m = 64;
        int t = ib + lane;
        int idx = (t < i1) ? csrc[t] : 0;
        float2 pp = pos2[idx];
        float ppx = pp.x, ppy = pp.y;
        int j = 0;
        for (; j + 4 <= m; j += 4) {
            float va[4], vb[4];
#pragma unroll
            for (int q = 0; q < 4; ++q) {
                size_t row = (size_t)rl_i(idx, j + q) * 104;
                va[q] = y[row + lane];
                vb[q] = y[row + chi];
            }
#pragma unroll
            for (int q = 0; q < 4; ++q) {
                float dx = rl_f(ppx, j + q) - pd.x, dy = rl_f(ppy, j + q) - pd.y;
                accA = fmaxf(accA, fmaf(dy, wa1, fmaf(dx, wa0, va[q])));
                accB = fmaxf(accB, fmaf(dy, wb1, fmaf(dx, wb0, vb[q])));
            }
        }
        for (; j < m; ++j) {
            size_t row = (size_t)rl_i(idx, j) * 104;
            float va = y[row + lane];
            float vb = y[row + chi];
            float dx = rl_f(ppx, j) - pd.x, dy = rl_f(ppy, j) - pd.y;
            accA = fmaxf(accA, fmaf(dy, wa1, fmaf(dx, wa0, va)));
            accB = fmaxf(accB, fmaf(dy, wb1, fmaf(dx, wb0, vb)));
        }
    }
    agg[(size_t)node * 104 + lane] = fmaxf(accA, 0.0f);
    if (lane + 64 < NCLS) agg[(size_t)node * 104 + 64 + lane] = fmaxf(accB, 0.0f);
}

// reg+obj: 5 channels packed stride 8; wave = 8 edge-slots x 8 channel-slots
__global__ __launch_bounds__(256) void edge_ro_k(const float* __restrict__ y,  // stride 8
                                                 const float2* __restrict__ pos2,
                                                 const int* __restrict__ rs,
                                                 const int* __restrict__ csrc,
                                                 const float* __restrict__ wro,  // (5,66)
                                                 float* __restrict__ aggr,
                                                 float* __restrict__ aggo) {
    int wid = __builtin_amdgcn_readfirstlane(threadIdx.x >> 6);
    int lane = threadIdx.x & 63;
    int node = blockIdx.x * 4 + wid;
    if (node >= NN) return;
    int k = lane >> 3, c = lane & 7;
    int cc = (c < 5) ? c : 4;
    float wp0 = wro[cc * 66 + 64], wp1 = wro[cc * 66 + 65];
    float2 pd = pos2[node];
    int i0 = rs[node], i1 = rs[node + 1];
    float acc = NINF;
    for (int i = i0 + k; i < i1; i += 8) {
        int s = csrc[i];
        float2 p = pos2[s];
        float v = y[(size_t)s * 8 + cc];
        acc = fmaxf(acc, fmaf(p.y - pd.y, wp1, fmaf(p.x - pd.x, wp0, v)));
    }
    acc = fmaxf(acc, __shfl_xor(acc, 8, 64));
    acc = fmaxf(acc, __shfl_xor(acc, 16, 64));
    acc = fmaxf(acc, __shfl_xor(acc, 32, 64));
    acc = fmaxf(acc, 0.0f);
    if (lane < 5) {
        if (lane < 4) aggr[(size_t)node * 4 + lane] = acc;
        else          aggo[node] = acc;
    }
}

// ============================================================================
// BN: column sums -> scale/shift params (apply is fused into consumer GEMM)
// ============================================================================
__global__ __launch_bounds__(256) void stats_k(const float* __restrict__ x,
                                               float* __restrict__ st) {
    __shared__ float sS[4][64], sQ[4][64];
    int wid = threadIdx.x >> 6, lane = threadIdx.x & 63;
    int stride = gridDim.x * 4;
    float s = 0.f, q = 0.f;
    for (int n = blockIdx.x * 4 + wid; n < NN; n += stride) {
        float v = x[(size_t)n * 64 + lane];
        s += v;
        q = fmaf(v, v, q);
    }
    sS[wid][lane] = s;
    sQ[wid][lane] = q;
    __syncthreads();
    if (wid == 0) {
        float ts = sS[0][lane] + sS[1][lane] + sS[2][lane] + sS[3][lane];
        float tq = sQ[0][lane] + sQ[1][lane] + sQ[2][lane] + sQ[3][lane];
        atomicAdd(&st[lane], ts);
        atomicAdd(&st[64 + lane], tq);
    }
}

__global__ void bnpar_k(float* __restrict__ st, const float* __restrict__ g,
                        const float* __restrict__ b) {
    int c = threadIdx.x;
    if (c >= 64) return;
    float mu = st[c] * (1.0f / NN);
    float var = st[64 + c] * (1.0f / NN) - mu * mu;
    float sc = g[c] * rsqrtf(var + EPS_BN);
    st[128 + c] = sc;
    st[192 + c] = b[c] - mu * sc;
}

__global__ __launch_bounds__(256) void final_ro_k(const float* __restrict__ aggr,
                                                  const float* __restrict__ aggo,
                                                  const float* __restrict__ wgr,
                                                  const float* __restrict__ bgr,
                                                  const float* __restrict__ wgo,
                                                  const float* __restrict__ bgo,
                                                  float* __restrict__ out) {
    int n = blockIdx.x * 256 + threadIdx.x;
    if (n >= NN) return;
    float a0 = aggr[(size_t)n * 4 + 0], a1 = aggr[(size_t)n * 4 + 1];
    float a2 = aggr[(size_t)n * 4 + 2], a3 = aggr[(size_t)n * 4 + 3];
    float* reg = out + (size_t)NN * NCLS;
    float* obj = reg + (size_t)NN * 4;
#pragma unroll
    for (int k = 0; k < 4; ++k) {
        float acc = bgr[k];
        acc = fmaf(a0, wgr[k * 4 + 0], acc);
        acc = fmaf(a1, wgr[k * 4 + 1], acc);
        acc = fmaf(a2, wgr[k * 4 + 2], acc);
        acc = fmaf(a3, wgr[k * 4 + 3], acc);
        reg[(size_t)n * 4 + k] = acc;
    }
    obj[n] = fmaf(aggo[n], wgo[0], bgo[0]);
}

// ============================================================================
extern "C" void kernel_launch(void* const* d_in, const int* in_sizes, int n_in,
                              void* d_out, int out_size, void* d_ws, size_t ws_size,
                              hipStream_t stream) {
    const float* x   = (const float*)d_in[0];
    const float* pos = (const float*)d_in[1];
    const int* ei    = (const int*)d_in[2];
    const int* src = ei;
    const int* dst = ei + NE;
    const float* wl_stem = (const float*)d_in[3];
    const float* bl_stem = (const float*)d_in[4];
    const float* wg_stem = (const float*)d_in[5];
    const float* bg_stem = (const float*)d_in[6];
    const float* g_stem  = (const float*)d_in[7];
    const float* b_stem  = (const float*)d_in[8];
    const float* wl_c1 = (const float*)d_in[9];
    const float* bl_c1 = (const float*)d_in[10];
    const float* wg_c1 = (const float*)d_in[11];
    const float* bg_c1 = (const float*)d_in[12];
    const float* g_c1  = (const float*)d_in[13];
    const float* b_c1  = (const float*)d_in[14];
    const float* wl_c2 = (const float*)d_in[15];
    const float* bl_c2 = (const float*)d_in[16];
    const float* wg_c2 = (const float*)d_in[17];
    const float* bg_c2 = (const float*)d_in[18];
    const float* g_c2  = (const float*)d_in[19];
    const float* b_c2  = (const float*)d_in[20];
    const float* wl_reg = (const float*)d_in[21];
    const float* bl_reg = (const float*)d_in[22];
    const float* wg_reg = (const float*)d_in[23];
    const float* bg_reg = (const float*)d_in[24];
    const float* wl_cls = (const float*)d_in[25];
    const float* bl_cls = (const float*)d_in[26];
    const float* wg_cls = (const float*)d_in[27];
    const float* bg_cls = (const float*)d_in[28];
    const float* wl_obj = (const float*)d_in[29];
    const float* bl_obj = (const float*)d_in[30];
    const float* wg_obj = (const float*)d_in[31];
    const float* bg_obj = (const float*)d_in[32];

    float* ws = (float*)d_ws;
    // Arena: S0[N*128] | S1[N*64] | S2[N*64] | S3[N*64] | ints/smalls
    float* S0 = ws;
    float* S1 = S0 + (size_t)NN * 128;
    float* S2 = S1 + (size_t)NN * 64;
    float* S3 = S2 + (size_t)NN * 64;
    float* y12   = S0;
    float* y_cls = S0;
    float* aggc  = S1;     // N*104 spans S1+S2 (both dead by then)
    int*   rs   = (int*)(S3 + (size_t)NN * 64);   // NN+1 (padded)
    int*   cnt  = rs + 100016;
    int*   csrc = cnt + 100016;                   // NE
    float* pos2 = (float*)(csrc + NE);            // NN float2
    float* y_ro = pos2 + (size_t)NN * 2;          // NN*8
    float* aggr = y_ro + (size_t)NN * 8;          // NN*4
    float* aggo = aggr + (size_t)NN * 4;          // NN
    float* st   = aggo + NN;                      // 3*256
    float* st0 = st, *st1 = st + 256, *st2 = st + 512;
    float* wro = st + 768;                        // 5*66 -> 336
    float* bro = wro + 336;                       // 8
    int*   blk = (int*)(bro + 8);                 // 512 scan block sums
    float* wT_sp = (float*)(blk + 512);           // [64][64]
    float* wT_sg = wT_sp + 4096;                  // [64][64]
    float* wT_12 = wT_sg + 4096;                  // [64][128]
    float* wT_g1 = wT_12 + 8192;                  // [64][64]
    float* wT_g2 = wT_g1 + 4096;                  // [64][64]
    float* wT_ro = wT_g2 + 4096;                  // [64][16]
    float* wT_cp = wT_ro + 1024;                  // [64][112]
    float* wT_cg = wT_cp + 7168;                  // [101][112]
    float* bAB   = wT_cg + 11312;                 // 128

    hipMemsetAsync(cnt, 0, 100016 * sizeof(int), stream);
    hipMemsetAsync(st, 0, 768 * sizeof(float), stream);

    const int EB = (NE + 255) / 256;      // 6250
    const int NB = (NN + 255) / 256;      // 391
    const int N4 = (NN + 3) / 4;          // 25000
    const int G128 = (NN + 127) / 128;    // 782
    const int G64  = (NN + 63) / 64;      // 1563

    // ---- packing + CSR build + pos2 ----
    pack_all_k<<<175, 256, 0, stream>>>(wl_stem, wg_stem, wl_c1, bl_c1, wl_c2,
                                        bl_c2, wg_c1, wg_c2, wl_reg, wl_obj,
                                        bl_reg, bl_obj, wl_cls, wg_cls,
                                        wT_sp, wT_sg, wT_12, wT_g1, wT_g2,
                                        wT_ro, wT_cp, wT_cg, bAB, wro, bro);
    pos2_k<<<NB, 256, 0, stream>>>(pos, (float2*)pos2);
    hist_k<<<EB, 256, 0, stream>>>(dst, cnt);
    scan1_k<<<NB_SCAN, 256, 0, stream>>>(cnt, rs, blk);
    scan2_k<<<1, 512, 0, stream>>>(blk);
    scan3_k<<<NB + 1, 256, 0, stream>>>(rs, blk, cnt);
    scatter_k<<<EB, 256, 0, stream>>>(src, dst, cnt, csrc);

    // ---- stem ----
    gemm_k<64, 16, 64, 64, 64, 128, false><<<G128, 256, 0, stream>>>(
        x, wT_sp, bl_stem, nullptr, S1);
    edge1_k<<<N4, 256, 0, stream>>>(S1, (float2*)pos2, rs, csrc, wl_stem, S2);
    gemm_k<64, 16, 64, 64, 64, 128, false><<<G128, 256, 0, stream>>>(
        S2, wT_sg, bg_stem, nullptr, S2);
    stats_k<<<512, 256, 0, stream>>>(S2, st0);
    bnpar_k<<<1, 64, 0, stream>>>(st0, g_stem, b_stem);

    // ---- c1 + c2 (BN fused into packed projection, shared edge pass) ----
    gemm_k<128, 32, 64, 64, 128, 128, true><<<G128, 256, 0, stream>>>(
        S2, wT_12, bAB, st0, y12);
    edge2_k<<<N4, 256, 0, stream>>>((const float2*)y12, (float2*)pos2, rs, csrc,
                                    wl_c1, wl_c2, S1, S3);
    gemm_k<64, 16, 64, 64, 64, 128, false><<<G128, 256, 0, stream>>>(
        S1, wT_g1, bg_c1, nullptr, S1);
    stats_k<<<512, 256, 0, stream>>>(S1, st1);
    bnpar_k<<<1, 64, 0, stream>>>(st1, g_c1, b_c1);
    gemm_k<64, 16, 64, 64, 64, 128, false><<<G128, 256, 0, stream>>>(
        S3, wT_g2, bg_c2, nullptr, S3);
    stats_k<<<512, 256, 0, stream>>>(S3, st2);
    bnpar_k<<<1, 64, 0, stream>>>(st2, g_c2, b_c2);

    // ---- reg + obj heads (input x1 = BN(S1), fused) ----
    gemm_k<5, 4, 64, 64, 8, 128, true><<<G128, 256, 0, stream>>>(
        S1, wT_ro, bro, st1, y_ro);
    edge_ro_k<<<N4, 256, 0, stream>>>(y_ro, (float2*)pos2, rs, csrc, wro, aggr, aggo);

    // ---- cls head (input x2 = BN(S3), fused) ----
    gemm_k<101, 28, 64, 64, 104, 128, true><<<G128, 256, 0, stream>>>(
        S3, wT_cp, bl_cls, st2, y_cls);
    edge_cls_k<<<N4, 256, 0, stream>>>(y_cls, (float2*)pos2, rs, csrc, wl_cls, aggc);
    gemm_k<101, 28, 101, 104, 101, 64, false><<<G64, 256, 0, stream>>>(
        aggc, wT_cg, bg_cls, nullptr, (float*)d_out);
    final_ro_k<<<NB, 256, 0, stream>>>(aggr, aggo, wg_reg, bg_reg, wg_obj, bg_obj,
                                       (float*)d_out);
}